// Round 1
// baseline (626.598 us; speedup 1.0000x reference)
//
#include <hip/hip_runtime.h>

#define H 128
#define IN_DIM 256
#define OUT_DIM 40
#define EPS 1e-5f

// ---------------- CSR build ----------------

__global__ __launch_bounds__(256) void count_kernel(const int* __restrict__ ei, int E, int* __restrict__ cnt) {
    int e = blockIdx.x * 256 + threadIdx.x;
    if (e < E) atomicAdd(&cnt[ei[E + e]], 1);   // col = target
}

__global__ __launch_bounds__(256) void dis_kernel(const int* __restrict__ cnt, float* __restrict__ dis, int N) {
    int i = blockIdx.x * 256 + threadIdx.x;
    if (i < N) dis[i] = rsqrtf((float)cnt[i] + 2.0f);   // improved=True: +2 self loop
}

__global__ __launch_bounds__(1024) void scan_kernel(const int* __restrict__ cnt, int* __restrict__ rowptr,
                                                    int* __restrict__ cursor, int N) {
    __shared__ int part[1024];
    int t = threadIdx.x;
    int chunk = (N + 1023) >> 10;
    int beg = t * chunk, end = min(beg + chunk, N);
    int s = 0;
    for (int i = beg; i < end; ++i) s += cnt[i];
    part[t] = s;
    __syncthreads();
    for (int off = 1; off < 1024; off <<= 1) {
        int v = (t >= off) ? part[t - off] : 0;
        __syncthreads();
        part[t] += v;
        __syncthreads();
    }
    int base = part[t] - s;  // exclusive
    for (int i = beg; i < end; ++i) { rowptr[i] = base; cursor[i] = base; base += cnt[i]; }
    if (t == 1023) rowptr[N] = part[1023];
}

__global__ __launch_bounds__(256) void fill_kernel(const int* __restrict__ ei, int E,
                                                   int* __restrict__ cursor, int* __restrict__ eidx) {
    int e = blockIdx.x * 256 + threadIdx.x;
    if (e < E) {
        int r = ei[e], c = ei[E + e];
        int slot = atomicAdd(&cursor[c], 1);
        eidx[slot] = r;
    }
}

// ---------------- GEMM: O = X[N,K] @ W[K,128] (optionally two W sharing X) ----------------
// BM=64 rows/block, BN=128 (full), K-chunk 32. 256 threads: 16x16, each 4 rows x 8 cols per matrix.

template <int K, bool DUAL>
__global__ __launch_bounds__(256) void gemm_kernel(const float* __restrict__ X,
                                                   const float* __restrict__ WA,
                                                   const float* __restrict__ WB,
                                                   const float* __restrict__ biasB,
                                                   float* __restrict__ OA,
                                                   float* __restrict__ OB,
                                                   int N) {
    __shared__ float xs[32][68];                      // [k][row], pad 68 -> 16B-aligned rows, 2-way max on read
    __shared__ float wa[32][128];
    __shared__ float wb[DUAL ? 32 : 1][DUAL ? 128 : 4];

    int tid = threadIdx.x;
    int brow = blockIdx.x * 64;
    int tr = tid >> 4, tc = tid & 15;

    float accA[4][8];
    float accB[4][8];
#pragma unroll
    for (int r = 0; r < 4; ++r)
#pragma unroll
        for (int j = 0; j < 8; ++j) { accA[r][j] = 0.f; accB[r][j] = 0.f; }

    for (int kc = 0; kc < K; kc += 32) {
        __syncthreads();
        // x tile: 64 rows x 32 k  (512 float4, 2 per thread), stored transposed
#pragma unroll
        for (int i = 0; i < 2; ++i) {
            int idx4 = tid + i * 256;
            int row = idx4 >> 3, k4 = idx4 & 7;
            float4 v = make_float4(0.f, 0.f, 0.f, 0.f);
            int grow = brow + row;
            if (grow < N) v = *(const float4*)&X[(size_t)grow * K + kc + k4 * 4];
            xs[k4 * 4 + 0][row] = v.x;
            xs[k4 * 4 + 1][row] = v.y;
            xs[k4 * 4 + 2][row] = v.z;
            xs[k4 * 4 + 3][row] = v.w;
        }
        // W tile(s): 32 x 128 (1024 float4, 4 per thread)
#pragma unroll
        for (int i = 0; i < 4; ++i) {
            int idx4 = tid + i * 256;
            int wrow = idx4 >> 5, wc4 = idx4 & 31;
            *(float4*)&wa[wrow][wc4 * 4] = *(const float4*)&WA[(size_t)(kc + wrow) * 128 + wc4 * 4];
            if constexpr (DUAL)
                *(float4*)&wb[wrow][wc4 * 4] = *(const float4*)&WB[(size_t)(kc + wrow) * 128 + wc4 * 4];
        }
        __syncthreads();
#pragma unroll
        for (int kk = 0; kk < 32; ++kk) {
            float4 a  = *(const float4*)&xs[kk][tr * 4];
            float4 w0 = *(const float4*)&wa[kk][tc * 4];
            float4 w1 = *(const float4*)&wa[kk][64 + tc * 4];
            float av[4] = {a.x, a.y, a.z, a.w};
            float w0v[4] = {w0.x, w0.y, w0.z, w0.w};
            float w1v[4] = {w1.x, w1.y, w1.z, w1.w};
#pragma unroll
            for (int r = 0; r < 4; ++r)
#pragma unroll
                for (int j = 0; j < 4; ++j) {
                    accA[r][j]     = fmaf(av[r], w0v[j], accA[r][j]);
                    accA[r][4 + j] = fmaf(av[r], w1v[j], accA[r][4 + j]);
                }
            if constexpr (DUAL) {
                float4 u0 = *(const float4*)&wb[kk][tc * 4];
                float4 u1 = *(const float4*)&wb[kk][64 + tc * 4];
                float u0v[4] = {u0.x, u0.y, u0.z, u0.w};
                float u1v[4] = {u1.x, u1.y, u1.z, u1.w};
#pragma unroll
                for (int r = 0; r < 4; ++r)
#pragma unroll
                    for (int j = 0; j < 4; ++j) {
                        accB[r][j]     = fmaf(av[r], u0v[j], accB[r][j]);
                        accB[r][4 + j] = fmaf(av[r], u1v[j], accB[r][4 + j]);
                    }
            }
        }
    }
    // store
#pragma unroll
    for (int r = 0; r < 4; ++r) {
        int grow = brow + tr * 4 + r;
        if (grow < N) {
            float4 s0 = make_float4(accA[r][0], accA[r][1], accA[r][2], accA[r][3]);
            float4 s1 = make_float4(accA[r][4], accA[r][5], accA[r][6], accA[r][7]);
            *(float4*)&OA[(size_t)grow * 128 + tc * 4]      = s0;
            *(float4*)&OA[(size_t)grow * 128 + 64 + tc * 4] = s1;
            if constexpr (DUAL) {
                float4 t0 = make_float4(accB[r][0] + biasB[tc * 4 + 0],
                                        accB[r][1] + biasB[tc * 4 + 1],
                                        accB[r][2] + biasB[tc * 4 + 2],
                                        accB[r][3] + biasB[tc * 4 + 3]);
                float4 t1 = make_float4(accB[r][4] + biasB[64 + tc * 4 + 0],
                                        accB[r][5] + biasB[64 + tc * 4 + 1],
                                        accB[r][6] + biasB[64 + tc * 4 + 2],
                                        accB[r][7] + biasB[64 + tc * 4 + 3]);
                *(float4*)&OB[(size_t)grow * 128 + tc * 4]      = t0;
                *(float4*)&OB[(size_t)grow * 128 + 64 + tc * 4] = t1;
            }
        }
    }
}

// ---------------- aggregation: one wave per node, 2 dims per lane, gather over CSR ----------------

__global__ __launch_bounds__(256) void aggregate_kernel(const float* __restrict__ h,
                                                        const int* __restrict__ rowptr,
                                                        const int* __restrict__ eidx,
                                                        const float* __restrict__ dis,
                                                        float* __restrict__ agg, int N) {
    int n = blockIdx.x * 4 + (threadIdx.x >> 6);
    int lane = threadIdx.x & 63;
    if (n >= N) return;
    int beg = rowptr[n], end = rowptr[n + 1];
    float dn = dis[n];
    const float2* h2 = (const float2*)h;
    float2 acc = make_float2(0.f, 0.f);
    for (int p = beg; p < end; ++p) {
        int src = eidx[p];
        float nrm = dis[src] * dn;
        float2 hv = h2[(size_t)src * 64 + lane];
        acc.x = fmaf(nrm, hv.x, acc.x);
        acc.y = fmaf(nrm, hv.y, acc.y);
    }
    float2 hv = h2[(size_t)n * 64 + lane];
    float w = 2.f * dn * dn;                 // self loop, fill=2.0
    acc.x = fmaf(w, hv.x, acc.x);
    acc.y = fmaf(w, hv.y, acc.y);
    ((float2*)agg)[(size_t)n * 64 + lane] = acc;
}

// ---------------- BN stats: each thread owns a fixed channel (stride % 128 == 0) ----------------

__global__ __launch_bounds__(256) void stats_kernel(const float* __restrict__ v, int total,
                                                    float* __restrict__ sums) {
    int tid = blockIdx.x * 256 + threadIdx.x;
    int stride = gridDim.x * 256;            // multiple of 128
    float s = 0.f, q = 0.f;
    for (int i = tid; i < total; i += stride) {
        float x = v[i];
        s += x;
        q = fmaf(x, x, q);
    }
    __shared__ float ls[256], lq[256];
    ls[threadIdx.x] = s;
    lq[threadIdx.x] = q;
    __syncthreads();
    if (threadIdx.x < 128) {
        float ss = ls[threadIdx.x] + ls[threadIdx.x + 128];
        float qq = lq[threadIdx.x] + lq[threadIdx.x + 128];
        int ch = threadIdx.x;                // == global channel, since blockDim=256
        atomicAdd(&sums[ch], ss);
        atomicAdd(&sums[128 + ch], qq);
    }
}

__global__ void bn_finalize(float* __restrict__ stats, const float* __restrict__ g,
                            const float* __restrict__ be, int N) {
    int c = threadIdx.x;                      // 128 threads
    float mean = stats[c] / (float)N;
    float var = stats[128 + c] / (float)N - mean * mean;   // biased
    float inv = rsqrtf(var + EPS);
    float sc = g[c] * inv;
    stats[c] = sc;
    stats[128 + c] = be[c] - mean * sc;
}

// out = relu(bnin*scale + shift) + addend   (out may alias bnin or addend elementwise)
__global__ __launch_bounds__(256) void bn_relu_add(const float* bnin, const float* __restrict__ stats,
                                                   const float* addend, float* out, int total) {
    int i = blockIdx.x * 256 + threadIdx.x;
    if (i < total) {
        int ch = i & 127;
        float v = fmaxf(fmaf(bnin[i], stats[ch], stats[128 + ch]), 0.f);
        out[i] = v + addend[i];
    }
}

// ---------------- head: out[N,40] = X[N,128] @ W[128,40] + b ----------------

__global__ __launch_bounds__(256) void head_kernel(const float* __restrict__ X, const float* __restrict__ W,
                                                   const float* __restrict__ b, float* __restrict__ out, int N) {
    int idx = blockIdx.x * 256 + threadIdx.x;
    if (idx >= N * OUT_DIM) return;
    int r = idx / OUT_DIM, c = idx - r * OUT_DIM;
    const float4* xr = (const float4*)&X[(size_t)r * H];
    float acc = b[c];
#pragma unroll
    for (int k4 = 0; k4 < 32; ++k4) {
        float4 xv = xr[k4];
        acc = fmaf(xv.x, W[(k4 * 4 + 0) * OUT_DIM + c], acc);
        acc = fmaf(xv.y, W[(k4 * 4 + 1) * OUT_DIM + c], acc);
        acc = fmaf(xv.z, W[(k4 * 4 + 2) * OUT_DIM + c], acc);
        acc = fmaf(xv.w, W[(k4 * 4 + 3) * OUT_DIM + c], acc);
    }
    out[idx] = acc;
}

// ---------------- launch ----------------

extern "C" void kernel_launch(void* const* d_in, const int* in_sizes, int n_in,
                              void* d_out, int out_size, void* d_ws, size_t ws_size,
                              hipStream_t stream) {
    const float* x   = (const float*)d_in[0];
    const int*   ei  = (const int*)d_in[1];
    const float* W0  = (const float*)d_in[2];
    // d_in[3] = b0: cancels exactly in BatchNorm -> skipped
    const float* g0  = (const float*)d_in[4];
    const float* be0 = (const float*)d_in[5];
    const float* pW  = (const float*)d_in[6];
    const float* pb  = (const float*)d_in[7];
    const float* W1  = (const float*)d_in[8];
    // d_in[9] = b1: cancels in BatchNorm
    const float* g1  = (const float*)d_in[10];
    const float* be1 = (const float*)d_in[11];
    const float* hW  = (const float*)d_in[12];
    const float* hb  = (const float*)d_in[13];
    float* out = (float*)d_out;

    int N = in_sizes[0] / IN_DIM;
    int E = in_sizes[1] / 2;
    size_t NH = (size_t)N * H;

    // workspace layout (floats/ints, 4B units): ~80.3 MB total
    float* h      = (float*)d_ws;            // [N,128]  (h0, then h1)
    float* agg    = h + NH;                  // [N,128]  (agg, then x2 in-place)
    float* x1b    = agg + NH;                // [N,128]  (proj, then x1 in-place)
    float* dis    = x1b + NH;                // [N]
    int*   cnt    = (int*)(dis + N);         // [N]
    int*   rowptr = cnt + N;                 // [N+1]
    int*   cursor = rowptr + (N + 1);        // [N]
    int*   eidx   = cursor + N;              // [E]
    float* stats  = (float*)(eidx + E);      // [256]

    int gE = (E + 255) / 256;
    int gN = (N + 255) / 256;
    int gRows = (N + 63) / 64;
    int gAgg = (N + 3) / 4;
    int gNH = (int)((NH + 255) / 256);

    // CSR build (shared by both convs)
    hipMemsetAsync(cnt, 0, (size_t)N * sizeof(int), stream);
    count_kernel<<<gE, 256, 0, stream>>>(ei, E, cnt);
    dis_kernel<<<gN, 256, 0, stream>>>(cnt, dis, N);
    scan_kernel<<<1, 1024, 0, stream>>>(cnt, rowptr, cursor, N);
    fill_kernel<<<gE, 256, 0, stream>>>(ei, E, cursor, eidx);

    // block 0
    gemm_kernel<IN_DIM, true><<<gRows, 256, 0, stream>>>(x, W0, pW, pb, h, x1b, N);
    aggregate_kernel<<<gAgg, 256, 0, stream>>>(h, rowptr, eidx, dis, agg, N);
    hipMemsetAsync(stats, 0, 256 * sizeof(float), stream);
    stats_kernel<<<256, 256, 0, stream>>>(agg, (int)NH, stats);
    bn_finalize<<<1, 128, 0, stream>>>(stats, g0, be0, N);
    bn_relu_add<<<gNH, 256, 0, stream>>>(agg, stats, x1b, x1b, (int)NH);   // x1 = relu(bn(agg)) + proj

    // block 1
    gemm_kernel<H, false><<<gRows, 256, 0, stream>>>(x1b, W1, nullptr, nullptr, h, nullptr, N);
    aggregate_kernel<<<gAgg, 256, 0, stream>>>(h, rowptr, eidx, dis, agg, N);
    hipMemsetAsync(stats, 0, 256 * sizeof(float), stream);
    stats_kernel<<<256, 256, 0, stream>>>(agg, (int)NH, stats);
    bn_finalize<<<1, 128, 0, stream>>>(stats, g1, be1, N);
    bn_relu_add<<<gNH, 256, 0, stream>>>(agg, stats, x1b, agg, (int)NH);   // x2 = relu(bn(agg)) + x1

    // head
    head_kernel<<<(N * OUT_DIM + 255) / 256, 256, 0, stream>>>(agg, hW, hb, out, N);
}

// Round 2
// 393.857 us; speedup vs baseline: 1.5909x; 1.5909x over previous
//
#include <hip/hip_runtime.h>

#define H 128
#define IN_DIM 256
#define OUT_DIM 40
#define EPS 1e-5f

typedef unsigned short ushortT;
typedef __attribute__((ext_vector_type(8))) short bf16x8;
typedef __attribute__((ext_vector_type(4))) float f32x4;

static __device__ __forceinline__ ushortT f2bf(float f) {
    union { float f; unsigned u; } v; v.f = f;
    unsigned r = v.u + 0x7FFF + ((v.u >> 16) & 1);   // RNE
    return (ushortT)(r >> 16);
}
static __device__ __forceinline__ unsigned pk2(float a, float b) {
    return (unsigned)f2bf(a) | ((unsigned)f2bf(b) << 16);
}

// ---------------- CSR build ----------------

__global__ __launch_bounds__(256) void count_kernel(const int* __restrict__ ei, int E, int* __restrict__ cnt) {
    int e = blockIdx.x * 256 + threadIdx.x;
    if (e < E) atomicAdd(&cnt[ei[E + e]], 1);   // col = target
}

__global__ __launch_bounds__(256) void dis_kernel(const int* __restrict__ cnt, float* __restrict__ dis, int N) {
    int i = blockIdx.x * 256 + threadIdx.x;
    if (i < N) dis[i] = rsqrtf((float)cnt[i] + 2.0f);   // improved=True: +2 self loop
}

__global__ __launch_bounds__(256) void scan_block_sum(const int* __restrict__ cnt, int* __restrict__ bsum, int N) {
    __shared__ int s[256];
    int i = blockIdx.x * 256 + threadIdx.x;
    s[threadIdx.x] = (i < N) ? cnt[i] : 0;
    __syncthreads();
    for (int o = 128; o > 0; o >>= 1) {
        if (threadIdx.x < o) s[threadIdx.x] += s[threadIdx.x + o];
        __syncthreads();
    }
    if (threadIdx.x == 0) bsum[blockIdx.x] = s[0];
}

__global__ void scan_tops(const int* __restrict__ bsum, int* __restrict__ boff, int* __restrict__ rowptrN, int nb) {
    __shared__ int s[256];
    int t = threadIdx.x;
    int v = (t < nb) ? bsum[t] : 0;
    s[t] = v;
    __syncthreads();
    for (int o = 1; o < 256; o <<= 1) {
        int u = (t >= o) ? s[t - o] : 0;
        __syncthreads();
        s[t] += u;
        __syncthreads();
    }
    if (t < nb) boff[t] = s[t] - v;
    if (t == 255) *rowptrN = s[255];
}

__global__ __launch_bounds__(256) void scan_final(const int* __restrict__ cnt, const int* __restrict__ boff,
                                                  int* __restrict__ rowptr, int* __restrict__ cursor, int N) {
    __shared__ int s[256];
    int t = threadIdx.x;
    int i = blockIdx.x * 256 + t;
    int v = (i < N) ? cnt[i] : 0;
    s[t] = v;
    __syncthreads();
    for (int o = 1; o < 256; o <<= 1) {
        int u = (t >= o) ? s[t - o] : 0;
        __syncthreads();
        s[t] += u;
        __syncthreads();
    }
    if (i < N) {
        int e = boff[blockIdx.x] + s[t] - v;
        rowptr[i] = e;
        cursor[i] = e;
    }
}

__global__ __launch_bounds__(256) void fill_kernel(const int* __restrict__ ei, int E,
                                                   int* __restrict__ cursor, int* __restrict__ eidx) {
    int e = blockIdx.x * 256 + threadIdx.x;
    if (e < E) {
        int r = ei[e], c = ei[E + e];
        int slot = atomicAdd(&cursor[c], 1);
        eidx[slot] = r;
    }
}

// ---------------- weight prep: transpose + bf16 ----------------
// Wt0/WtP: [128][256], Wt1: [128][128], WtH: [48][128] (cols 40..47 zero)

__global__ __launch_bounds__(256) void prep_weights(const float* __restrict__ W0, const float* __restrict__ pW,
                                                    const float* __restrict__ W1, const float* __restrict__ hW,
                                                    ushortT* __restrict__ Wt0, ushortT* __restrict__ WtP,
                                                    ushortT* __restrict__ Wt1, ushortT* __restrict__ WtH) {
    int i = blockIdx.x * 256 + threadIdx.x;
    if (i < 32768) { int n = i >> 8, k = i & 255; Wt0[i] = f2bf(W0[k * 128 + n]); WtP[i] = f2bf(pW[k * 128 + n]); }
    if (i < 16384) { int n = i >> 7, k = i & 127; Wt1[i] = f2bf(W1[k * 128 + n]); }
    if (i < 6144)  { int n = i >> 7, k = i & 127; WtH[i] = (n < OUT_DIM) ? f2bf(hW[k * OUT_DIM + n]) : (ushortT)0; }
}

// ---------------- MFMA GEMM: O = X[N,K]fp32 @ W[K,128], W given transposed bf16 Wt[128][K] ----------------
// block: 256 threads (4 waves), BM=64 rows, BN=128. wave w owns cols [32w,32w+32).
// K-step 32. DUAL computes a second matrix sharing the A tile.

template <int K, bool DUAL>
__global__ __launch_bounds__(256) void mgemm(const float* __restrict__ X,
                                             const ushortT* __restrict__ WtA,
                                             const ushortT* __restrict__ WtB,
                                             const float* __restrict__ biasB,
                                             float* __restrict__ OA,
                                             float* __restrict__ OB,
                                             int N) {
    __shared__ __align__(16) ushortT As[64][40];                     // pad 40 -> uniform bank tiling
    __shared__ __align__(16) ushortT Bs[DUAL ? 2 : 1][128][40];

    int tid = threadIdx.x;
    int brow = blockIdx.x * 64;
    int w = tid >> 6, lane = tid & 63;
    int lm = lane & 15, lk = lane >> 4;

    f32x4 accA[4][2];
    f32x4 accB[4][2];
#pragma unroll
    for (int mt = 0; mt < 4; ++mt)
#pragma unroll
        for (int nt = 0; nt < 2; ++nt) { accA[mt][nt] = (f32x4)0.f; accB[mt][nt] = (f32x4)0.f; }

    for (int kc = 0; kc < K; kc += 32) {
        __syncthreads();
        // A tile: 64 rows x 32 k, fp32 -> bf16
        {
            int row = tid >> 2, q = tid & 3;
            int gr = brow + row;
            float4 v0 = make_float4(0.f, 0.f, 0.f, 0.f), v1 = v0;
            if (gr < N) {
                const float4* p = (const float4*)&X[(size_t)gr * K + kc + q * 8];
                v0 = p[0]; v1 = p[1];
            }
            uint4 pkv;
            pkv.x = pk2(v0.x, v0.y);
            pkv.y = pk2(v0.z, v0.w);
            pkv.z = pk2(v1.x, v1.y);
            pkv.w = pk2(v1.z, v1.w);
            *(uint4*)&As[row][q * 8] = pkv;
        }
        // B tile(s): [128][32] bf16 from Wt rows (contiguous 64B each)
        if constexpr (DUAL) {
            int mat = tid >> 7, n = tid & 127;
            const ushortT* Wt = mat ? WtB : WtA;
            const uint4* src = (const uint4*)&Wt[(size_t)n * K + kc];
            uint4 a = src[0], b = src[1], c = src[2], d = src[3];
            uint4* dst = (uint4*)&Bs[mat][n][0];
            dst[0] = a; dst[1] = b; dst[2] = c; dst[3] = d;
        } else {
            int n = tid >> 1, hf = tid & 1;
            const uint4* src = (const uint4*)&WtA[(size_t)n * K + kc + hf * 16];
            uint4 a = src[0], b = src[1];
            uint4* dst = (uint4*)&Bs[0][n][hf * 16];
            dst[0] = a; dst[1] = b;
        }
        __syncthreads();

        bf16x8 af[4];
#pragma unroll
        for (int mt = 0; mt < 4; ++mt)
            af[mt] = *(const bf16x8*)&As[mt * 16 + lm][lk * 8];
#pragma unroll
        for (int nt = 0; nt < 2; ++nt) {
            bf16x8 b0 = *(const bf16x8*)&Bs[0][w * 32 + nt * 16 + lm][lk * 8];
#pragma unroll
            for (int mt = 0; mt < 4; ++mt)
                accA[mt][nt] = __builtin_amdgcn_mfma_f32_16x16x32_bf16(af[mt], b0, accA[mt][nt], 0, 0, 0);
            if constexpr (DUAL) {
                bf16x8 b1 = *(const bf16x8*)&Bs[1][w * 32 + nt * 16 + lm][lk * 8];
#pragma unroll
                for (int mt = 0; mt < 4; ++mt)
                    accB[mt][nt] = __builtin_amdgcn_mfma_f32_16x16x32_bf16(af[mt], b1, accB[mt][nt], 0, 0, 0);
            }
        }
    }

    float bb[2] = {0.f, 0.f};
    if constexpr (DUAL) {
#pragma unroll
        for (int nt = 0; nt < 2; ++nt) bb[nt] = biasB[w * 32 + nt * 16 + lm];
    }
#pragma unroll
    for (int mt = 0; mt < 4; ++mt) {
        int r0 = brow + mt * 16 + lk * 4;
#pragma unroll
        for (int nt = 0; nt < 2; ++nt) {
            int col = w * 32 + nt * 16 + lm;
#pragma unroll
            for (int j = 0; j < 4; ++j) {
                int r = r0 + j;
                if (r < N) {
                    OA[(size_t)r * 128 + col] = accA[mt][nt][j];
                    if constexpr (DUAL) OB[(size_t)r * 128 + col] = accB[mt][nt][j] + bb[nt];
                }
            }
        }
    }
}

// ---------------- head: out[N,40] = X[N,128] @ hW + hb via MFMA (cols padded to 48) ----------------

__global__ __launch_bounds__(256) void head_mfma(const float* __restrict__ X, const ushortT* __restrict__ WtH,
                                                 const float* __restrict__ hb, float* __restrict__ out, int N) {
    __shared__ __align__(16) ushortT As[64][136];
    __shared__ __align__(16) ushortT Bs[48][136];

    int tid = threadIdx.x;
    int brow = blockIdx.x * 64;
    int w = tid >> 6, lane = tid & 63;
    int lm = lane & 15, lk = lane >> 4;

    // stage A: 64 rows x 128 k fp32 -> bf16
    {
        int row = tid >> 2, q = tid & 3;
        int gr = brow + row;
        const float4* p = (const float4*)&X[(size_t)gr * H + q * 32];
#pragma unroll
        for (int c = 0; c < 4; ++c) {
            float4 v0 = make_float4(0.f, 0.f, 0.f, 0.f), v1 = v0;
            if (gr < N) { v0 = p[c * 2]; v1 = p[c * 2 + 1]; }
            uint4 pkv;
            pkv.x = pk2(v0.x, v0.y);
            pkv.y = pk2(v0.z, v0.w);
            pkv.z = pk2(v1.x, v1.y);
            pkv.w = pk2(v1.z, v1.w);
            *(uint4*)&As[row][q * 32 + c * 8] = pkv;
        }
    }
    // stage B: 48 rows x 128 bf16
    if (tid < 192) {
        int row = tid >> 2, q = tid & 3;
        const uint4* src = (const uint4*)&WtH[(size_t)row * H + q * 32];
        uint4 a = src[0], b = src[1], c = src[2], d = src[3];
        uint4* dst = (uint4*)&Bs[row][q * 32];
        dst[0] = a; dst[1] = b; dst[2] = c; dst[3] = d;
    }
    __syncthreads();

    f32x4 acc[3];
#pragma unroll
    for (int nt = 0; nt < 3; ++nt) acc[nt] = (f32x4)0.f;
#pragma unroll
    for (int ks = 0; ks < 4; ++ks) {
        bf16x8 a = *(const bf16x8*)&As[w * 16 + lm][ks * 32 + lk * 8];
#pragma unroll
        for (int nt = 0; nt < 3; ++nt) {
            bf16x8 b = *(const bf16x8*)&Bs[nt * 16 + lm][ks * 32 + lk * 8];
            acc[nt] = __builtin_amdgcn_mfma_f32_16x16x32_bf16(a, b, acc[nt], 0, 0, 0);
        }
    }
#pragma unroll
    for (int nt = 0; nt < 3; ++nt) {
        int col = nt * 16 + lm;
        if (col < OUT_DIM) {
            float bbv = hb[col];
#pragma unroll
            for (int j = 0; j < 4; ++j) {
                int r = brow + w * 16 + lk * 4 + j;
                if (r < N) out[(size_t)r * OUT_DIM + col] = acc[nt][j] + bbv;
            }
        }
    }
}

// ---------------- aggregation: one wave per node, 2 dims per lane, gather over CSR ----------------

__global__ __launch_bounds__(256) void aggregate_kernel(const float* __restrict__ h,
                                                        const int* __restrict__ rowptr,
                                                        const int* __restrict__ eidx,
                                                        const float* __restrict__ dis,
                                                        float* __restrict__ agg, int N) {
    int n = blockIdx.x * 4 + (threadIdx.x >> 6);
    int lane = threadIdx.x & 63;
    if (n >= N) return;
    int beg = rowptr[n], end = rowptr[n + 1];
    float dn = dis[n];
    const float2* h2 = (const float2*)h;
    float2 acc = make_float2(0.f, 0.f);
    for (int p = beg; p < end; ++p) {
        int src = eidx[p];
        float nrm = dis[src] * dn;
        float2 hv = h2[(size_t)src * 64 + lane];
        acc.x = fmaf(nrm, hv.x, acc.x);
        acc.y = fmaf(nrm, hv.y, acc.y);
    }
    float2 hv = h2[(size_t)n * 64 + lane];
    float sw = 2.f * dn * dn;                 // self loop, fill=2.0
    acc.x = fmaf(sw, hv.x, acc.x);
    acc.y = fmaf(sw, hv.y, acc.y);
    ((float2*)agg)[(size_t)n * 64 + lane] = acc;
}

// ---------------- BN stats ----------------

__global__ __launch_bounds__(256) void stats_kernel(const float* __restrict__ v, int total,
                                                    float* __restrict__ sums) {
    int tid = blockIdx.x * 256 + threadIdx.x;
    int stride = gridDim.x * 256;            // multiple of 128
    float s = 0.f, q = 0.f;
    for (int i = tid; i < total; i += stride) {
        float x = v[i];
        s += x;
        q = fmaf(x, x, q);
    }
    __shared__ float ls[256], lq[256];
    ls[threadIdx.x] = s;
    lq[threadIdx.x] = q;
    __syncthreads();
    if (threadIdx.x < 128) {
        float ss = ls[threadIdx.x] + ls[threadIdx.x + 128];
        float qq = lq[threadIdx.x] + lq[threadIdx.x + 128];
        int ch = threadIdx.x;
        atomicAdd(&sums[ch], ss);
        atomicAdd(&sums[128 + ch], qq);
    }
}

__global__ void bn_finalize(float* __restrict__ stats, const float* __restrict__ g,
                            const float* __restrict__ be, int N) {
    int c = threadIdx.x;                      // 128 threads
    float mean = stats[c] / (float)N;
    float var = stats[128 + c] / (float)N - mean * mean;   // biased
    float inv = rsqrtf(var + EPS);
    float sc = g[c] * inv;
    stats[c] = sc;
    stats[128 + c] = be[c] - mean * sc;
}

__global__ __launch_bounds__(256) void bn_relu_add(const float* bnin, const float* __restrict__ stats,
                                                   const float* addend, float* out, int total) {
    int i = blockIdx.x * 256 + threadIdx.x;
    if (i < total) {
        int ch = i & 127;
        float v = fmaxf(fmaf(bnin[i], stats[ch], stats[128 + ch]), 0.f);
        out[i] = v + addend[i];
    }
}

// ---------------- launch ----------------

extern "C" void kernel_launch(void* const* d_in, const int* in_sizes, int n_in,
                              void* d_out, int out_size, void* d_ws, size_t ws_size,
                              hipStream_t stream) {
    const float* x   = (const float*)d_in[0];
    const int*   ei  = (const int*)d_in[1];
    const float* W0  = (const float*)d_in[2];
    // d_in[3] = b0: cancels in BatchNorm
    const float* g0  = (const float*)d_in[4];
    const float* be0 = (const float*)d_in[5];
    const float* pW  = (const float*)d_in[6];
    const float* pb  = (const float*)d_in[7];
    const float* W1  = (const float*)d_in[8];
    // d_in[9] = b1: cancels in BatchNorm
    const float* g1  = (const float*)d_in[10];
    const float* be1 = (const float*)d_in[11];
    const float* hW  = (const float*)d_in[12];
    const float* hb  = (const float*)d_in[13];
    float* out = (float*)d_out;

    int N = in_sizes[0] / IN_DIM;
    int E = in_sizes[1] / 2;
    size_t NH = (size_t)N * H;

    // workspace layout
    float*   h      = (float*)d_ws;            // [N,128]
    float*   agg    = h + NH;                  // [N,128]
    float*   x1b    = agg + NH;                // [N,128]
    float*   dis    = x1b + NH;                // [N]
    int*     cnt    = (int*)(dis + N);         // [N]
    int*     rowptr = cnt + N;                 // [N+1]
    int*     cursor = rowptr + (N + 1);        // [N]
    int*     eidx   = cursor + N;              // [E]
    float*   stats  = (float*)(eidx + E);      // [256]
    ushortT* Wt0    = (ushortT*)(stats + 256); // [128*256]
    ushortT* WtP    = Wt0 + 128 * 256;         // [128*256]
    ushortT* Wt1    = WtP + 128 * 256;         // [128*128]
    ushortT* WtH    = Wt1 + 128 * 128;         // [48*128]
    int*     bsum   = (int*)(WtH + 48 * 128);  // [256]
    int*     boff   = bsum + 256;              // [256]

    int gE = (E + 255) / 256;
    int gN = (N + 255) / 256;
    int nb = (N + 255) / 256;
    int gRows = (N + 63) / 64;
    int gAgg = (N + 3) / 4;
    int gNH = (int)((NH + 255) / 256);

    // CSR build + weight prep
    hipMemsetAsync(cnt, 0, (size_t)N * sizeof(int), stream);
    prep_weights<<<128, 256, 0, stream>>>(W0, pW, W1, hW, Wt0, WtP, Wt1, WtH);
    count_kernel<<<gE, 256, 0, stream>>>(ei, E, cnt);
    dis_kernel<<<gN, 256, 0, stream>>>(cnt, dis, N);
    scan_block_sum<<<nb, 256, 0, stream>>>(cnt, bsum, N);
    scan_tops<<<1, 256, 0, stream>>>(bsum, boff, &rowptr[N], nb);
    scan_final<<<nb, 256, 0, stream>>>(cnt, boff, rowptr, cursor, N);
    fill_kernel<<<gE, 256, 0, stream>>>(ei, E, cursor, eidx);

    // block 0
    mgemm<IN_DIM, true><<<gRows, 256, 0, stream>>>(x, Wt0, WtP, pb, h, x1b, N);
    aggregate_kernel<<<gAgg, 256, 0, stream>>>(h, rowptr, eidx, dis, agg, N);
    hipMemsetAsync(stats, 0, 256 * sizeof(float), stream);
    stats_kernel<<<256, 256, 0, stream>>>(agg, (int)NH, stats);
    bn_finalize<<<1, 128, 0, stream>>>(stats, g0, be0, N);
    bn_relu_add<<<gNH, 256, 0, stream>>>(agg, stats, x1b, x1b, (int)NH);   // x1 = relu(bn(agg)) + proj

    // block 1
    mgemm<H, false><<<gRows, 256, 0, stream>>>(x1b, Wt1, nullptr, nullptr, h, nullptr, N);
    aggregate_kernel<<<gAgg, 256, 0, stream>>>(h, rowptr, eidx, dis, agg, N);
    hipMemsetAsync(stats, 0, 256 * sizeof(float), stream);
    stats_kernel<<<256, 256, 0, stream>>>(agg, (int)NH, stats);
    bn_finalize<<<1, 128, 0, stream>>>(stats, g1, be1, N);
    bn_relu_add<<<gNH, 256, 0, stream>>>(agg, stats, x1b, agg, (int)NH);   // x2 = relu(bn(agg)) + x1

    // head
    head_mfma<<<gRows, 256, 0, stream>>>(agg, WtH, hb, out, N);
}

// Round 3
// 367.979 us; speedup vs baseline: 1.7028x; 1.0703x over previous
//
#include <hip/hip_runtime.h>

#define H 128
#define IN_DIM 256
#define OUT_DIM 40
#define EPS 1e-5f

typedef unsigned short ushortT;
typedef __attribute__((ext_vector_type(8))) short bf16x8;
typedef __attribute__((ext_vector_type(4))) float f32x4;

static __device__ __forceinline__ ushortT f2bf(float f) {
    union { float f; unsigned u; } v; v.f = f;
    unsigned r = v.u + 0x7FFF + ((v.u >> 16) & 1);   // RNE
    return (ushortT)(r >> 16);
}
static __device__ __forceinline__ unsigned pk2(float a, float b) {
    return (unsigned)f2bf(a) | ((unsigned)f2bf(b) << 16);
}
static __device__ __forceinline__ float bflo(unsigned v) {
    union { unsigned u; float f; } t; t.u = v << 16; return t.f;
}
static __device__ __forceinline__ float bfhi(unsigned v) {
    union { unsigned u; float f; } t; t.u = v & 0xFFFF0000u; return t.f;
}

// ---------------- CSR build ----------------

__global__ __launch_bounds__(256) void count_kernel(const int* __restrict__ ei, int E, int* __restrict__ cnt) {
    int e = blockIdx.x * 256 + threadIdx.x;
    if (e < E) atomicAdd(&cnt[ei[E + e]], 1);   // col = target
}

__global__ __launch_bounds__(256) void scan_block_sum(const int* __restrict__ cnt, int* __restrict__ bsum,
                                                      float* __restrict__ dis, int N) {
    __shared__ int s[256];
    int i = blockIdx.x * 256 + threadIdx.x;
    int v = (i < N) ? cnt[i] : 0;
    if (i < N) dis[i] = rsqrtf((float)v + 2.0f);       // improved=True: +2 self loop
    s[threadIdx.x] = v;
    __syncthreads();
    for (int o = 128; o > 0; o >>= 1) {
        if (threadIdx.x < o) s[threadIdx.x] += s[threadIdx.x + o];
        __syncthreads();
    }
    if (threadIdx.x == 0) bsum[blockIdx.x] = s[0];
}

__global__ void scan_tops(const int* __restrict__ bsum, int* __restrict__ boff, int* __restrict__ rowptrN, int nb) {
    __shared__ int s[256];
    int t = threadIdx.x;
    int v = (t < nb) ? bsum[t] : 0;
    s[t] = v;
    __syncthreads();
    for (int o = 1; o < 256; o <<= 1) {
        int u = (t >= o) ? s[t - o] : 0;
        __syncthreads();
        s[t] += u;
        __syncthreads();
    }
    if (t < nb) boff[t] = s[t] - v;
    if (t == 255) *rowptrN = s[255];
}

__global__ __launch_bounds__(256) void scan_final(const int* __restrict__ cnt, const int* __restrict__ boff,
                                                  int* __restrict__ rowptr, int* __restrict__ cursor, int N) {
    __shared__ int s[256];
    int t = threadIdx.x;
    int i = blockIdx.x * 256 + t;
    int v = (i < N) ? cnt[i] : 0;
    s[t] = v;
    __syncthreads();
    for (int o = 1; o < 256; o <<= 1) {
        int u = (t >= o) ? s[t - o] : 0;
        __syncthreads();
        s[t] += u;
        __syncthreads();
    }
    if (i < N) {
        int e = boff[blockIdx.x] + s[t] - v;
        rowptr[i] = e;
        cursor[i] = e;
    }
}

__global__ __launch_bounds__(256) void fill_kernel(const int* __restrict__ ei, int E,
                                                   int* __restrict__ cursor, int* __restrict__ eidx) {
    int e = blockIdx.x * 256 + threadIdx.x;
    if (e < E) {
        int r = ei[e], c = ei[E + e];
        int slot = atomicAdd(&cursor[c], 1);
        eidx[slot] = r;
    }
}

// ---------------- weight prep: transpose + bf16 ----------------

__global__ __launch_bounds__(256) void prep_weights(const float* __restrict__ W0, const float* __restrict__ pW,
                                                    const float* __restrict__ W1, const float* __restrict__ hW,
                                                    ushortT* __restrict__ Wt0, ushortT* __restrict__ WtP,
                                                    ushortT* __restrict__ Wt1, ushortT* __restrict__ WtH) {
    int i = blockIdx.x * 256 + threadIdx.x;
    if (i < 32768) { int n = i >> 8, k = i & 255; Wt0[i] = f2bf(W0[k * 128 + n]); WtP[i] = f2bf(pW[k * 128 + n]); }
    if (i < 16384) { int n = i >> 7, k = i & 127; Wt1[i] = f2bf(W1[k * 128 + n]); }
    if (i < 6144)  { int n = i >> 7, k = i & 127; WtH[i] = (n < OUT_DIM) ? f2bf(hW[k * OUT_DIM + n]) : (ushortT)0; }
}

// ---------------- MFMA GEMM: OA(bf16) = X[N,K] @ WtA^T ; optional OB(fp32) = X @ WtB^T + biasB ----------------
// 256 threads (4 waves), BM=64, BN=128, K-step 32. wave w owns cols [32w,32w+32).

template <int K, bool DUAL, bool ABF16>
__global__ __launch_bounds__(256) void mgemm(const float* __restrict__ Xf,
                                             const ushortT* __restrict__ Xb,
                                             const ushortT* __restrict__ WtA,
                                             const ushortT* __restrict__ WtB,
                                             const float* __restrict__ biasB,
                                             ushortT* __restrict__ OA,
                                             float* __restrict__ OB,
                                             int N) {
    __shared__ __align__(16) ushortT As[64][40];
    __shared__ __align__(16) ushortT Bs[DUAL ? 2 : 1][128][40];

    int tid = threadIdx.x;
    int brow = blockIdx.x * 64;
    int w = tid >> 6, lane = tid & 63;
    int lm = lane & 15, lk = lane >> 4;

    f32x4 accA[4][2];
    f32x4 accB[4][2];
#pragma unroll
    for (int mt = 0; mt < 4; ++mt)
#pragma unroll
        for (int nt = 0; nt < 2; ++nt) { accA[mt][nt] = (f32x4)0.f; accB[mt][nt] = (f32x4)0.f; }

    for (int kc = 0; kc < K; kc += 32) {
        __syncthreads();
        // A tile: 64 rows x 32 k
        if constexpr (!ABF16) {
            int row = tid >> 2, q = tid & 3;
            int gr = brow + row;
            float4 v0 = make_float4(0.f, 0.f, 0.f, 0.f), v1 = v0;
            if (gr < N) {
                const float4* p = (const float4*)&Xf[(size_t)gr * K + kc + q * 8];
                v0 = p[0]; v1 = p[1];
            }
            uint4 pkv;
            pkv.x = pk2(v0.x, v0.y);
            pkv.y = pk2(v0.z, v0.w);
            pkv.z = pk2(v1.x, v1.y);
            pkv.w = pk2(v1.z, v1.w);
            *(uint4*)&As[row][q * 8] = pkv;
        } else {
            int row = tid >> 2, q = tid & 3;
            int gr = brow + row;
            uint4 v = make_uint4(0u, 0u, 0u, 0u);
            if (gr < N) v = *(const uint4*)&Xb[(size_t)gr * K + kc + q * 8];
            *(uint4*)&As[row][q * 8] = v;
        }
        // B tile(s)
        if constexpr (DUAL) {
            int mat = tid >> 7, n = tid & 127;
            const ushortT* Wt = mat ? WtB : WtA;
            const uint4* src = (const uint4*)&Wt[(size_t)n * K + kc];
            uint4 a = src[0], b = src[1], c = src[2], d = src[3];
            uint4* dst = (uint4*)&Bs[mat][n][0];
            dst[0] = a; dst[1] = b; dst[2] = c; dst[3] = d;
        } else {
            int n = tid >> 1, hf = tid & 1;
            const uint4* src = (const uint4*)&WtA[(size_t)n * K + kc + hf * 16];
            uint4 a = src[0], b = src[1];
            uint4* dst = (uint4*)&Bs[0][n][hf * 16];
            dst[0] = a; dst[1] = b;
        }
        __syncthreads();

        bf16x8 af[4];
#pragma unroll
        for (int mt = 0; mt < 4; ++mt)
            af[mt] = *(const bf16x8*)&As[mt * 16 + lm][lk * 8];
#pragma unroll
        for (int nt = 0; nt < 2; ++nt) {
            bf16x8 b0 = *(const bf16x8*)&Bs[0][w * 32 + nt * 16 + lm][lk * 8];
#pragma unroll
            for (int mt = 0; mt < 4; ++mt)
                accA[mt][nt] = __builtin_amdgcn_mfma_f32_16x16x32_bf16(af[mt], b0, accA[mt][nt], 0, 0, 0);
            if constexpr (DUAL) {
                bf16x8 b1 = *(const bf16x8*)&Bs[1][w * 32 + nt * 16 + lm][lk * 8];
#pragma unroll
                for (int mt = 0; mt < 4; ++mt)
                    accB[mt][nt] = __builtin_amdgcn_mfma_f32_16x16x32_bf16(af[mt], b1, accB[mt][nt], 0, 0, 0);
            }
        }
    }

    float bb[2] = {0.f, 0.f};
    if constexpr (DUAL) {
#pragma unroll
        for (int nt = 0; nt < 2; ++nt) bb[nt] = biasB[w * 32 + nt * 16 + lm];
    }
#pragma unroll
    for (int mt = 0; mt < 4; ++mt) {
        int r0 = brow + mt * 16 + lk * 4;
#pragma unroll
        for (int nt = 0; nt < 2; ++nt) {
            int col = w * 32 + nt * 16 + lm;
#pragma unroll
            for (int j = 0; j < 4; ++j) {
                int r = r0 + j;
                if (r < N) {
                    OA[(size_t)r * 128 + col] = f2bf(accA[mt][nt][j]);
                    if constexpr (DUAL) OB[(size_t)r * 128 + col] = accB[mt][nt][j] + bb[nt];
                }
            }
        }
    }
}

// ---------------- aggregation: one wave per node, bf16 gather, fp32 accumulate ----------------

__global__ __launch_bounds__(256) void aggregate_bf(const ushortT* __restrict__ h,
                                                    const int* __restrict__ rowptr,
                                                    const int* __restrict__ eidx,
                                                    const float* __restrict__ dis,
                                                    float* __restrict__ agg, int N) {
    int n = blockIdx.x * 4 + (threadIdx.x >> 6);
    int lane = threadIdx.x & 63;
    if (n >= N) return;
    int beg = rowptr[n], end = rowptr[n + 1];
    float dn = dis[n];
    const unsigned* h1 = (const unsigned*)h;     // 2 bf16 per uint
    float ax = 0.f, ay = 0.f;
    float bx = 0.f, by = 0.f;
    int p = beg;
    for (; p + 1 < end; p += 2) {
        int s0 = eidx[p], s1 = eidx[p + 1];
        float n0 = dis[s0] * dn, n1 = dis[s1] * dn;
        unsigned v0 = h1[(size_t)s0 * 64 + lane];
        unsigned v1 = h1[(size_t)s1 * 64 + lane];
        ax = fmaf(n0, bflo(v0), ax);
        ay = fmaf(n0, bfhi(v0), ay);
        bx = fmaf(n1, bflo(v1), bx);
        by = fmaf(n1, bfhi(v1), by);
    }
    if (p < end) {
        int s0 = eidx[p];
        float n0 = dis[s0] * dn;
        unsigned v0 = h1[(size_t)s0 * 64 + lane];
        ax = fmaf(n0, bflo(v0), ax);
        ay = fmaf(n0, bfhi(v0), ay);
    }
    {
        unsigned v = h1[(size_t)n * 64 + lane];
        float sw = 2.f * dn * dn;                // self loop, fill=2.0
        ax = fmaf(sw, bflo(v), ax);
        ay = fmaf(sw, bfhi(v), ay);
    }
    ((float2*)agg)[(size_t)n * 64 + lane] = make_float2(ax + bx, ay + by);
}

// ---------------- BN stats (raw sums) ----------------

__global__ __launch_bounds__(256) void stats_kernel(const float* __restrict__ v, int total,
                                                    float* __restrict__ sums) {
    int tid = blockIdx.x * 256 + threadIdx.x;
    int stride = gridDim.x * 256;            // multiple of 128
    float s = 0.f, q = 0.f;
    for (int i = tid; i < total; i += stride) {
        float x = v[i];
        s += x;
        q = fmaf(x, x, q);
    }
    __shared__ float ls[256], lq[256];
    ls[threadIdx.x] = s;
    lq[threadIdx.x] = q;
    __syncthreads();
    if (threadIdx.x < 128) {
        float ss = ls[threadIdx.x] + ls[threadIdx.x + 128];
        float qq = lq[threadIdx.x] + lq[threadIdx.x + 128];
        int ch = threadIdx.x;
        atomicAdd(&sums[ch], ss);
        atomicAdd(&sums[128 + ch], qq);
    }
}

// x1 = relu(bn(agg)) + addend; writes fp32 and bf16 copies. scale/shift derived in-block.
__global__ __launch_bounds__(256) void bn_relu_add_v2(const float* __restrict__ agg,
                                                      const float* __restrict__ stats,
                                                      const float* __restrict__ g,
                                                      const float* __restrict__ be,
                                                      const float* __restrict__ addend,
                                                      float* __restrict__ x1f,
                                                      ushortT* __restrict__ x1b, int N) {
    __shared__ float sc[128], sh[128];
    int t = threadIdx.x;
    if (t < 128) {
        float mean = stats[t] / (float)N;
        float var = stats[128 + t] / (float)N - mean * mean;
        float inv = rsqrtf(var + EPS);
        float s = g[t] * inv;
        sc[t] = s;
        sh[t] = be[t] - mean * s;
    }
    __syncthreads();
    size_t i4 = (size_t)blockIdx.x * 256 + t;      // float4 index
    size_t total4 = (size_t)N * 32;
    if (i4 >= total4) return;
    int ch = (int)(i4 & 31) * 4;
    float4 a = ((const float4*)agg)[i4];
    float4 d = ((const float4*)addend)[i4];
    float4 r;
    r.x = fmaxf(fmaf(a.x, sc[ch + 0], sh[ch + 0]), 0.f) + d.x;
    r.y = fmaxf(fmaf(a.y, sc[ch + 1], sh[ch + 1]), 0.f) + d.y;
    r.z = fmaxf(fmaf(a.z, sc[ch + 2], sh[ch + 2]), 0.f) + d.z;
    r.w = fmaxf(fmaf(a.w, sc[ch + 3], sh[ch + 3]), 0.f) + d.w;
    ((float4*)x1f)[i4] = r;
    uint2 pb2;
    pb2.x = pk2(r.x, r.y);
    pb2.y = pk2(r.z, r.w);
    ((uint2*)x1b)[i4] = pb2;
}

// ---------------- head: out = (relu(bn(agg)) + x1) @ hW + hb, x2 computed inline ----------------

__global__ __launch_bounds__(256) void head_fused(const float* __restrict__ agg,
                                                  const float* __restrict__ x1f,
                                                  const float* __restrict__ stats,
                                                  const float* __restrict__ g,
                                                  const float* __restrict__ be,
                                                  const ushortT* __restrict__ WtH,
                                                  const float* __restrict__ hb,
                                                  float* __restrict__ out, int N) {
    __shared__ __align__(16) ushortT As[64][136];
    __shared__ __align__(16) ushortT Bs[48][136];
    __shared__ float sc[128], sh[128];

    int tid = threadIdx.x;
    int brow = blockIdx.x * 64;
    int w = tid >> 6, lane = tid & 63;
    int lm = lane & 15, lk = lane >> 4;

    if (tid < 128) {
        float mean = stats[tid] / (float)N;
        float var = stats[128 + tid] / (float)N - mean * mean;
        float inv = rsqrtf(var + EPS);
        float s = g[tid] * inv;
        sc[tid] = s;
        sh[tid] = be[tid] - mean * s;
    }
    // stage B: 48 rows x 128 bf16 (no dependence on sc/sh)
    if (tid < 192) {
        int row = tid >> 2, q = tid & 3;
        const uint4* src = (const uint4*)&WtH[(size_t)row * H + q * 32];
        uint4 a = src[0], b = src[1], c = src[2], d = src[3];
        uint4* dst = (uint4*)&Bs[row][q * 32];
        dst[0] = a; dst[1] = b; dst[2] = c; dst[3] = d;
    }
    __syncthreads();
    // stage A: x2 = relu(bn(agg)) + x1, fp32 -> bf16
    {
        int row = tid >> 2, q = tid & 3;
        int gr = brow + row;
        const float4* pa = (const float4*)&agg[(size_t)gr * H + q * 32];
        const float4* px = (const float4*)&x1f[(size_t)gr * H + q * 32];
#pragma unroll
        for (int c = 0; c < 8; ++c) {
            float4 a = make_float4(0.f, 0.f, 0.f, 0.f), d = a;
            if (gr < N) { a = pa[c]; d = px[c]; }
            int k = q * 32 + c * 4;
            float v0 = fmaxf(fmaf(a.x, sc[k + 0], sh[k + 0]), 0.f) + d.x;
            float v1 = fmaxf(fmaf(a.y, sc[k + 1], sh[k + 1]), 0.f) + d.y;
            float v2 = fmaxf(fmaf(a.z, sc[k + 2], sh[k + 2]), 0.f) + d.z;
            float v3 = fmaxf(fmaf(a.w, sc[k + 3], sh[k + 3]), 0.f) + d.w;
            uint2 pv;
            pv.x = pk2(v0, v1);
            pv.y = pk2(v2, v3);
            *(uint2*)&As[row][k] = pv;
        }
    }
    __syncthreads();

    f32x4 acc[3];
#pragma unroll
    for (int nt = 0; nt < 3; ++nt) acc[nt] = (f32x4)0.f;
#pragma unroll
    for (int ks = 0; ks < 4; ++ks) {
        bf16x8 a = *(const bf16x8*)&As[w * 16 + lm][ks * 32 + lk * 8];
#pragma unroll
        for (int nt = 0; nt < 3; ++nt) {
            bf16x8 b = *(const bf16x8*)&Bs[nt * 16 + lm][ks * 32 + lk * 8];
            acc[nt] = __builtin_amdgcn_mfma_f32_16x16x32_bf16(a, b, acc[nt], 0, 0, 0);
        }
    }
#pragma unroll
    for (int nt = 0; nt < 3; ++nt) {
        int col = nt * 16 + lm;
        if (col < OUT_DIM) {
            float bbv = hb[col];
#pragma unroll
            for (int j = 0; j < 4; ++j) {
                int r = brow + w * 16 + lk * 4 + j;
                if (r < N) out[(size_t)r * OUT_DIM + col] = acc[nt][j] + bbv;
            }
        }
    }
}

// ---------------- launch ----------------

extern "C" void kernel_launch(void* const* d_in, const int* in_sizes, int n_in,
                              void* d_out, int out_size, void* d_ws, size_t ws_size,
                              hipStream_t stream) {
    const float* x   = (const float*)d_in[0];
    const int*   ei  = (const int*)d_in[1];
    const float* W0  = (const float*)d_in[2];
    // d_in[3] = b0: cancels in BatchNorm
    const float* g0  = (const float*)d_in[4];
    const float* be0 = (const float*)d_in[5];
    const float* pW  = (const float*)d_in[6];
    const float* pb  = (const float*)d_in[7];
    const float* W1  = (const float*)d_in[8];
    // d_in[9] = b1: cancels in BatchNorm
    const float* g1  = (const float*)d_in[10];
    const float* be1 = (const float*)d_in[11];
    const float* hW  = (const float*)d_in[12];
    const float* hb  = (const float*)d_in[13];
    float* out = (float*)d_out;

    int N = in_sizes[0] / IN_DIM;
    int E = in_sizes[1] / 2;
    size_t NH = (size_t)N * H;

    // workspace layout
    ushortT* hb16   = (ushortT*)d_ws;            // [N,128] bf16
    float*   agg    = (float*)(hb16 + NH);       // [N,128] fp32
    float*   x1f    = agg + NH;                  // [N,128] fp32
    ushortT* x1b16  = (ushortT*)(x1f + NH);      // [N,128] bf16
    float*   dis    = (float*)(x1b16 + NH);      // [N]
    int*     cnt    = (int*)(dis + N);           // [N]
    int*     rowptr = cnt + N;                   // [N+1]
    int*     cursor = rowptr + (N + 1);          // [N]
    int*     eidx   = cursor + N;                // [E]
    float*   stats  = (float*)(eidx + E);        // [256]
    ushortT* Wt0    = (ushortT*)(stats + 256);   // [128*256]
    ushortT* WtP    = Wt0 + 128 * 256;           // [128*256]
    ushortT* Wt1    = WtP + 128 * 256;           // [128*128]
    ushortT* WtH    = Wt1 + 128 * 128;           // [48*128]
    int*     bsum   = (int*)(WtH + 48 * 128);    // [256]
    int*     boff   = bsum + 256;                // [256]

    int gE = (E + 255) / 256;
    int nb = (N + 255) / 256;
    int gRows = (N + 63) / 64;
    int gAgg = (N + 3) / 4;
    int gNH4 = (int)((NH / 4 + 255) / 256);

    // CSR build + weight prep
    hipMemsetAsync(cnt, 0, (size_t)N * sizeof(int), stream);
    prep_weights<<<128, 256, 0, stream>>>(W0, pW, W1, hW, Wt0, WtP, Wt1, WtH);
    count_kernel<<<gE, 256, 0, stream>>>(ei, E, cnt);
    scan_block_sum<<<nb, 256, 0, stream>>>(cnt, bsum, dis, N);
    scan_tops<<<1, 256, 0, stream>>>(bsum, boff, &rowptr[N], nb);
    scan_final<<<nb, 256, 0, stream>>>(cnt, boff, rowptr, cursor, N);
    fill_kernel<<<gE, 256, 0, stream>>>(ei, E, cursor, eidx);

    // block 0
    mgemm<IN_DIM, true, false><<<gRows, 256, 0, stream>>>(x, nullptr, Wt0, WtP, pb, hb16, x1f, N);
    aggregate_bf<<<gAgg, 256, 0, stream>>>(hb16, rowptr, eidx, dis, agg, N);
    hipMemsetAsync(stats, 0, 256 * sizeof(float), stream);
    stats_kernel<<<256, 256, 0, stream>>>(agg, (int)NH, stats);
    bn_relu_add_v2<<<gNH4, 256, 0, stream>>>(agg, stats, g0, be0, x1f, x1f, x1b16, N);

    // block 1
    mgemm<H, false, true><<<gRows, 256, 0, stream>>>(nullptr, x1b16, Wt1, nullptr, nullptr, hb16, nullptr, N);
    aggregate_bf<<<gAgg, 256, 0, stream>>>(hb16, rowptr, eidx, dis, agg, N);
    hipMemsetAsync(stats, 0, 256 * sizeof(float), stream);
    stats_kernel<<<256, 256, 0, stream>>>(agg, (int)NH, stats);

    // head (x2 computed inline)
    head_fused<<<gRows, 256, 0, stream>>>(agg, x1f, stats, g1, be1, WtH, hb, out, N);
}

// Round 4
// 279.456 us; speedup vs baseline: 2.2422x; 1.3168x over previous
//
#include <hip/hip_runtime.h>

#define H 128
#define IN_DIM 256
#define OUT_DIM 40
#define EPS 1e-5f

typedef unsigned short ushortT;
typedef __attribute__((ext_vector_type(8))) short bf16x8;
typedef __attribute__((ext_vector_type(4))) float f32x4;

static __device__ __forceinline__ ushortT f2bf(float f) {
    union { float f; unsigned u; } v; v.f = f;
    unsigned r = v.u + 0x7FFF + ((v.u >> 16) & 1);   // RNE
    return (ushortT)(r >> 16);
}
static __device__ __forceinline__ unsigned pk2(float a, float b) {
    return (unsigned)f2bf(a) | ((unsigned)f2bf(b) << 16);
}
static __device__ __forceinline__ float bflo(unsigned v) {
    union { unsigned u; float f; } t; t.u = v << 16; return t.f;
}
static __device__ __forceinline__ float bfhi(unsigned v) {
    union { unsigned u; float f; } t; t.u = v & 0xFFFF0000u; return t.f;
}

// ---------------- CSR build ----------------

__global__ __launch_bounds__(256) void count_kernel(const int* __restrict__ ei, int E, int* __restrict__ cnt) {
    int e = blockIdx.x * 256 + threadIdx.x;
    if (e < E) atomicAdd(&cnt[ei[E + e]], 1);   // col = target
}

__global__ __launch_bounds__(256) void scan_block_sum(const int* __restrict__ cnt, int* __restrict__ bsum,
                                                      float* __restrict__ dis, int N) {
    __shared__ int s[256];
    int i = blockIdx.x * 256 + threadIdx.x;
    int v = (i < N) ? cnt[i] : 0;
    if (i < N) dis[i] = rsqrtf((float)v + 2.0f);       // improved=True: +2 self loop
    s[threadIdx.x] = v;
    __syncthreads();
    for (int o = 128; o > 0; o >>= 1) {
        if (threadIdx.x < o) s[threadIdx.x] += s[threadIdx.x + o];
        __syncthreads();
    }
    if (threadIdx.x == 0) bsum[blockIdx.x] = s[0];
}

__global__ void scan_tops(const int* __restrict__ bsum, int* __restrict__ boff, int* __restrict__ rowptrN, int nb) {
    __shared__ int s[256];
    int t = threadIdx.x;
    int v = (t < nb) ? bsum[t] : 0;
    s[t] = v;
    __syncthreads();
    for (int o = 1; o < 256; o <<= 1) {
        int u = (t >= o) ? s[t - o] : 0;
        __syncthreads();
        s[t] += u;
        __syncthreads();
    }
    if (t < nb) boff[t] = s[t] - v;
    if (t == 255) *rowptrN = s[255];
}

__global__ __launch_bounds__(256) void scan_final(const int* __restrict__ cnt, const int* __restrict__ boff,
                                                  int* __restrict__ rowptr, int* __restrict__ cursor, int N) {
    __shared__ int s[256];
    int t = threadIdx.x;
    int i = blockIdx.x * 256 + t;
    int v = (i < N) ? cnt[i] : 0;
    s[t] = v;
    __syncthreads();
    for (int o = 1; o < 256; o <<= 1) {
        int u = (t >= o) ? s[t - o] : 0;
        __syncthreads();
        s[t] += u;
        __syncthreads();
    }
    if (i < N) {
        int e = boff[blockIdx.x] + s[t] - v;
        rowptr[i] = e;
        cursor[i] = e;
    }
}

__global__ __launch_bounds__(256) void fill_kernel(const int* __restrict__ ei, int E,
                                                   int* __restrict__ cursor, int* __restrict__ eidx) {
    int e = blockIdx.x * 256 + threadIdx.x;
    if (e < E) {
        int r = ei[e], c = ei[E + e];
        int slot = atomicAdd(&cursor[c], 1);
        eidx[slot] = r;
    }
}

// ---------------- weight prep: transpose + bf16 ----------------

__global__ __launch_bounds__(256) void prep_weights(const float* __restrict__ W0, const float* __restrict__ pW,
                                                    const float* __restrict__ W1, const float* __restrict__ hW,
                                                    ushortT* __restrict__ Wt0, ushortT* __restrict__ WtP,
                                                    ushortT* __restrict__ Wt1, ushortT* __restrict__ WtH) {
    int i = blockIdx.x * 256 + threadIdx.x;
    if (i < 32768) { int n = i >> 8, k = i & 255; Wt0[i] = f2bf(W0[k * 128 + n]); WtP[i] = f2bf(pW[k * 128 + n]); }
    if (i < 16384) { int n = i >> 7, k = i & 127; Wt1[i] = f2bf(W1[k * 128 + n]); }
    if (i < 6144)  { int n = i >> 7, k = i & 127; WtH[i] = (n < OUT_DIM) ? f2bf(hW[k * OUT_DIM + n]) : (ushortT)0; }
}

// ---------------- MFMA GEMM: OA(bf16) = X @ WtA^T ; optional OB(bf16) = X @ WtB^T + biasB ----------------
// 256 threads (4 waves), BM=64, BN=128, K-step 32. wave w owns cols [32w,32w+32).

template <int K, bool DUAL, bool ABF16>
__global__ __launch_bounds__(256) void mgemm(const float* __restrict__ Xf,
                                             const ushortT* __restrict__ Xb,
                                             const ushortT* __restrict__ WtA,
                                             const ushortT* __restrict__ WtB,
                                             const float* __restrict__ biasB,
                                             ushortT* __restrict__ OA,
                                             ushortT* __restrict__ OB,
                                             int N) {
    __shared__ __align__(16) ushortT As[64][40];
    __shared__ __align__(16) ushortT Bs[DUAL ? 2 : 1][128][40];

    int tid = threadIdx.x;
    int brow = blockIdx.x * 64;
    int w = tid >> 6, lane = tid & 63;
    int lm = lane & 15, lk = lane >> 4;

    f32x4 accA[4][2];
    f32x4 accB[4][2];
#pragma unroll
    for (int mt = 0; mt < 4; ++mt)
#pragma unroll
        for (int nt = 0; nt < 2; ++nt) { accA[mt][nt] = (f32x4)0.f; accB[mt][nt] = (f32x4)0.f; }

    for (int kc = 0; kc < K; kc += 32) {
        __syncthreads();
        // A tile: 64 rows x 32 k
        if constexpr (!ABF16) {
            int row = tid >> 2, q = tid & 3;
            int gr = brow + row;
            float4 v0 = make_float4(0.f, 0.f, 0.f, 0.f), v1 = v0;
            if (gr < N) {
                const float4* p = (const float4*)&Xf[(size_t)gr * K + kc + q * 8];
                v0 = p[0]; v1 = p[1];
            }
            uint4 pkv;
            pkv.x = pk2(v0.x, v0.y);
            pkv.y = pk2(v0.z, v0.w);
            pkv.z = pk2(v1.x, v1.y);
            pkv.w = pk2(v1.z, v1.w);
            *(uint4*)&As[row][q * 8] = pkv;
        } else {
            int row = tid >> 2, q = tid & 3;
            int gr = brow + row;
            uint4 v = make_uint4(0u, 0u, 0u, 0u);
            if (gr < N) v = *(const uint4*)&Xb[(size_t)gr * K + kc + q * 8];
            *(uint4*)&As[row][q * 8] = v;
        }
        // B tile(s)
        if constexpr (DUAL) {
            int mat = tid >> 7, n = tid & 127;
            const ushortT* Wt = mat ? WtB : WtA;
            const uint4* src = (const uint4*)&Wt[(size_t)n * K + kc];
            uint4 a = src[0], b = src[1], c = src[2], d = src[3];
            uint4* dst = (uint4*)&Bs[mat][n][0];
            dst[0] = a; dst[1] = b; dst[2] = c; dst[3] = d;
        } else {
            int n = tid >> 1, hf = tid & 1;
            const uint4* src = (const uint4*)&WtA[(size_t)n * K + kc + hf * 16];
            uint4 a = src[0], b = src[1];
            uint4* dst = (uint4*)&Bs[0][n][hf * 16];
            dst[0] = a; dst[1] = b;
        }
        __syncthreads();

        bf16x8 af[4];
#pragma unroll
        for (int mt = 0; mt < 4; ++mt)
            af[mt] = *(const bf16x8*)&As[mt * 16 + lm][lk * 8];
#pragma unroll
        for (int nt = 0; nt < 2; ++nt) {
            bf16x8 b0 = *(const bf16x8*)&Bs[0][w * 32 + nt * 16 + lm][lk * 8];
#pragma unroll
            for (int mt = 0; mt < 4; ++mt)
                accA[mt][nt] = __builtin_amdgcn_mfma_f32_16x16x32_bf16(af[mt], b0, accA[mt][nt], 0, 0, 0);
            if constexpr (DUAL) {
                bf16x8 b1 = *(const bf16x8*)&Bs[1][w * 32 + nt * 16 + lm][lk * 8];
#pragma unroll
                for (int mt = 0; mt < 4; ++mt)
                    accB[mt][nt] = __builtin_amdgcn_mfma_f32_16x16x32_bf16(af[mt], b1, accB[mt][nt], 0, 0, 0);
            }
        }
    }

    float bb[2] = {0.f, 0.f};
    if constexpr (DUAL) {
#pragma unroll
        for (int nt = 0; nt < 2; ++nt) bb[nt] = biasB[w * 32 + nt * 16 + lm];
    }
#pragma unroll
    for (int mt = 0; mt < 4; ++mt) {
        int r0 = brow + mt * 16 + lk * 4;
#pragma unroll
        for (int nt = 0; nt < 2; ++nt) {
            int col = w * 32 + nt * 16 + lm;
#pragma unroll
            for (int j = 0; j < 4; ++j) {
                int r = r0 + j;
                if (r < N) {
                    OA[(size_t)r * 128 + col] = f2bf(accA[mt][nt][j]);
                    if constexpr (DUAL) OB[(size_t)r * 128 + col] = f2bf(accB[mt][nt][j] + bb[nt]);
                }
            }
        }
    }
}

// ---------------- aggregation: one wave per node, bf16 gather, fp32 accumulate, bf16 out ----------------

__global__ __launch_bounds__(256) void aggregate_bf(const ushortT* __restrict__ h,
                                                    const int* __restrict__ rowptr,
                                                    const int* __restrict__ eidx,
                                                    const float* __restrict__ dis,
                                                    ushortT* __restrict__ aggb, int N) {
    int n = blockIdx.x * 4 + (threadIdx.x >> 6);
    int lane = threadIdx.x & 63;
    if (n >= N) return;
    int beg = rowptr[n], end = rowptr[n + 1];
    float dn = dis[n];
    const unsigned* h1 = (const unsigned*)h;     // 2 bf16 per uint
    float a0x = 0.f, a0y = 0.f, a1x = 0.f, a1y = 0.f;
    float a2x = 0.f, a2y = 0.f, a3x = 0.f, a3y = 0.f;
    int p = beg;
    for (; p + 3 < end; p += 4) {
        int s0 = eidx[p], s1 = eidx[p + 1], s2 = eidx[p + 2], s3 = eidx[p + 3];
        float n0 = dis[s0] * dn, n1 = dis[s1] * dn, n2 = dis[s2] * dn, n3 = dis[s3] * dn;
        unsigned v0 = h1[(size_t)s0 * 64 + lane];
        unsigned v1 = h1[(size_t)s1 * 64 + lane];
        unsigned v2 = h1[(size_t)s2 * 64 + lane];
        unsigned v3 = h1[(size_t)s3 * 64 + lane];
        a0x = fmaf(n0, bflo(v0), a0x); a0y = fmaf(n0, bfhi(v0), a0y);
        a1x = fmaf(n1, bflo(v1), a1x); a1y = fmaf(n1, bfhi(v1), a1y);
        a2x = fmaf(n2, bflo(v2), a2x); a2y = fmaf(n2, bfhi(v2), a2y);
        a3x = fmaf(n3, bflo(v3), a3x); a3y = fmaf(n3, bfhi(v3), a3y);
    }
    for (; p < end; ++p) {
        int s0 = eidx[p];
        float n0 = dis[s0] * dn;
        unsigned v0 = h1[(size_t)s0 * 64 + lane];
        a0x = fmaf(n0, bflo(v0), a0x); a0y = fmaf(n0, bfhi(v0), a0y);
    }
    {
        unsigned v = h1[(size_t)n * 64 + lane];
        float sw = 2.f * dn * dn;                // self loop, fill=2.0
        a0x = fmaf(sw, bflo(v), a0x); a0y = fmaf(sw, bfhi(v), a0y);
    }
    float rx = (a0x + a1x) + (a2x + a3x);
    float ry = (a0y + a1y) + (a2y + a3y);
    ((unsigned*)aggb)[(size_t)n * 64 + lane] = pk2(rx, ry);
}

// ---------------- BN stats from bf16 (raw sums) ----------------
// grid*block must be a multiple of 64: thread's channel pair is fixed: ch = 2*(tid&63).

__global__ __launch_bounds__(256) void stats_bf(const unsigned* __restrict__ v, int totalU,
                                                float* __restrict__ sums) {
    int tid = blockIdx.x * 256 + threadIdx.x;
    int stride = gridDim.x * 256;
    float sx = 0.f, sy = 0.f, qx = 0.f, qy = 0.f;
    for (int i = tid; i < totalU; i += stride) {
        unsigned u = v[i];
        float a = bflo(u), b = bfhi(u);
        sx += a; sy += b;
        qx = fmaf(a, a, qx); qy = fmaf(b, b, qy);
    }
    __shared__ float l0[256], l1[256], l2[256], l3[256];
    int t = threadIdx.x;
    l0[t] = sx; l1[t] = sy; l2[t] = qx; l3[t] = qy;
    __syncthreads();
    if (t < 64) {
        sx = (l0[t] + l0[t + 64]) + (l0[t + 128] + l0[t + 192]);
        sy = (l1[t] + l1[t + 64]) + (l1[t + 128] + l1[t + 192]);
        qx = (l2[t] + l2[t + 64]) + (l2[t + 128] + l2[t + 192]);
        qy = (l3[t] + l3[t + 64]) + (l3[t + 128] + l3[t + 192]);
        atomicAdd(&sums[2 * t], sx);
        atomicAdd(&sums[2 * t + 1], sy);
        atomicAdd(&sums[128 + 2 * t], qx);
        atomicAdd(&sums[128 + 2 * t + 1], qy);
    }
}

// ---------------- x1 = relu(bn(agg)) + proj, all bf16 ----------------
// uint2 = 4 bf16; channel base = (i2 & 31) * 4.

__global__ __launch_bounds__(256) void bn_relu_add_v3(const uint2* __restrict__ aggb,
                                                      const float* __restrict__ stats,
                                                      const float* __restrict__ g,
                                                      const float* __restrict__ be,
                                                      const uint2* __restrict__ projb,
                                                      uint2* __restrict__ x1b, int N) {
    __shared__ float sc[128], sh[128];
    int t = threadIdx.x;
    if (t < 128) {
        float mean = stats[t] / (float)N;
        float var = stats[128 + t] / (float)N - mean * mean;
        float inv = rsqrtf(var + EPS);
        float s = g[t] * inv;
        sc[t] = s;
        sh[t] = be[t] - mean * s;
    }
    __syncthreads();
    size_t i2 = (size_t)blockIdx.x * 256 + t;
    size_t total2 = (size_t)N * 32;
    if (i2 >= total2) return;
    int ch = (int)(i2 & 31) * 4;
    uint2 a = aggb[i2];
    uint2 d = projb[i2];
    float v0 = fmaxf(fmaf(bflo(a.x), sc[ch + 0], sh[ch + 0]), 0.f) + bflo(d.x);
    float v1 = fmaxf(fmaf(bfhi(a.x), sc[ch + 1], sh[ch + 1]), 0.f) + bfhi(d.x);
    float v2 = fmaxf(fmaf(bflo(a.y), sc[ch + 2], sh[ch + 2]), 0.f) + bflo(d.y);
    float v3 = fmaxf(fmaf(bfhi(a.y), sc[ch + 3], sh[ch + 3]), 0.f) + bfhi(d.y);
    uint2 r;
    r.x = pk2(v0, v1);
    r.y = pk2(v2, v3);
    x1b[i2] = r;
}

// ---------------- head: out = (relu(bn(agg)) + x1) @ hW + hb, x2 inline, coalesced staging ----------------

__global__ __launch_bounds__(256) void head_fused(const uint4* __restrict__ aggb,
                                                  const uint4* __restrict__ x1b,
                                                  const float* __restrict__ stats,
                                                  const float* __restrict__ g,
                                                  const float* __restrict__ be,
                                                  const ushortT* __restrict__ WtH,
                                                  const float* __restrict__ hb,
                                                  float* __restrict__ out, int N) {
    __shared__ __align__(16) ushortT As[64][136];
    __shared__ __align__(16) ushortT Bs[48][136];
    __shared__ float sc[128], sh[128];

    int tid = threadIdx.x;
    int brow = blockIdx.x * 64;
    int w = tid >> 6, lane = tid & 63;
    int lm = lane & 15, lk = lane >> 4;

    if (tid < 128) {
        float mean = stats[tid] / (float)N;
        float var = stats[128 + tid] / (float)N - mean * mean;
        float inv = rsqrtf(var + EPS);
        float s = g[tid] * inv;
        sc[tid] = s;
        sh[tid] = be[tid] - mean * s;
    }
    // stage B: 48 rows x 128 bf16
    if (tid < 192) {
        int row = tid >> 2, q = tid & 3;
        const uint4* src = (const uint4*)&WtH[(size_t)row * H + q * 32];
        uint4 a = src[0], b = src[1], c = src[2], d = src[3];
        uint4* dst = (uint4*)&Bs[row][q * 32];
        dst[0] = a; dst[1] = b; dst[2] = c; dst[3] = d;
    }
    __syncthreads();
    // stage A: flat coalesced; uint4 idx covers 8 bf16. row = idx>>4, colq = idx&15.
#pragma unroll
    for (int k = 0; k < 4; ++k) {
        int idx = k * 256 + tid;
        int row = idx >> 4, colq = idx & 15;
        int gr = brow + row;
        uint4 a = make_uint4(0u, 0u, 0u, 0u), x = a;
        if (gr < N) {
            size_t gidx = (size_t)brow * 16 + idx;
            a = aggb[gidx];
            x = x1b[gidx];
        }
        int ch = colq * 8;
        float v0 = fmaxf(fmaf(bflo(a.x), sc[ch + 0], sh[ch + 0]), 0.f) + bflo(x.x);
        float v1 = fmaxf(fmaf(bfhi(a.x), sc[ch + 1], sh[ch + 1]), 0.f) + bfhi(x.x);
        float v2 = fmaxf(fmaf(bflo(a.y), sc[ch + 2], sh[ch + 2]), 0.f) + bflo(x.y);
        float v3 = fmaxf(fmaf(bfhi(a.y), sc[ch + 3], sh[ch + 3]), 0.f) + bfhi(x.y);
        float v4 = fmaxf(fmaf(bflo(a.z), sc[ch + 4], sh[ch + 4]), 0.f) + bflo(x.z);
        float v5 = fmaxf(fmaf(bfhi(a.z), sc[ch + 5], sh[ch + 5]), 0.f) + bfhi(x.z);
        float v6 = fmaxf(fmaf(bflo(a.w), sc[ch + 6], sh[ch + 6]), 0.f) + bflo(x.w);
        float v7 = fmaxf(fmaf(bfhi(a.w), sc[ch + 7], sh[ch + 7]), 0.f) + bfhi(x.w);
        uint4 pv;
        pv.x = pk2(v0, v1);
        pv.y = pk2(v2, v3);
        pv.z = pk2(v4, v5);
        pv.w = pk2(v6, v7);
        *(uint4*)&As[row][colq * 8] = pv;
    }
    __syncthreads();

    f32x4 acc[3];
#pragma unroll
    for (int nt = 0; nt < 3; ++nt) acc[nt] = (f32x4)0.f;
#pragma unroll
    for (int ks = 0; ks < 4; ++ks) {
        bf16x8 a = *(const bf16x8*)&As[w * 16 + lm][ks * 32 + lk * 8];
#pragma unroll
        for (int nt = 0; nt < 3; ++nt) {
            bf16x8 b = *(const bf16x8*)&Bs[nt * 16 + lm][ks * 32 + lk * 8];
            acc[nt] = __builtin_amdgcn_mfma_f32_16x16x32_bf16(a, b, acc[nt], 0, 0, 0);
        }
    }
#pragma unroll
    for (int nt = 0; nt < 3; ++nt) {
        int col = nt * 16 + lm;
        if (col < OUT_DIM) {
            float bbv = hb[col];
#pragma unroll
            for (int j = 0; j < 4; ++j) {
                int r = brow + w * 16 + lk * 4 + j;
                if (r < N) out[(size_t)r * OUT_DIM + col] = acc[nt][j] + bbv;
            }
        }
    }
}

// ---------------- launch ----------------

extern "C" void kernel_launch(void* const* d_in, const int* in_sizes, int n_in,
                              void* d_out, int out_size, void* d_ws, size_t ws_size,
                              hipStream_t stream) {
    const float* x   = (const float*)d_in[0];
    const int*   ei  = (const int*)d_in[1];
    const float* W0  = (const float*)d_in[2];
    // d_in[3] = b0: cancels in BatchNorm
    const float* g0  = (const float*)d_in[4];
    const float* be0 = (const float*)d_in[5];
    const float* pW  = (const float*)d_in[6];
    const float* pb  = (const float*)d_in[7];
    const float* W1  = (const float*)d_in[8];
    // d_in[9] = b1: cancels in BatchNorm
    const float* g1  = (const float*)d_in[10];
    const float* be1 = (const float*)d_in[11];
    const float* hW  = (const float*)d_in[12];
    const float* hb  = (const float*)d_in[13];
    float* out = (float*)d_out;

    int N = in_sizes[0] / IN_DIM;
    int E = in_sizes[1] / 2;
    size_t NH = (size_t)N * H;

    // workspace layout (all bf16 intermediates)
    ushortT* hb16   = (ushortT*)d_ws;            // [N,128] conv input h
    ushortT* aggb   = hb16 + NH;                 // [N,128] aggregated
    ushortT* projb  = aggb + NH;                 // [N,128] proj (block0)
    ushortT* x1b    = projb + NH;                // [N,128] x1
    float*   dis    = (float*)(x1b + NH);        // [N]
    int*     cnt    = (int*)(dis + N);           // [N]
    int*     rowptr = cnt + N;                   // [N+1]
    int*     cursor = rowptr + (N + 1);          // [N]
    int*     eidx   = cursor + N;                // [E]
    float*   stats  = (float*)(eidx + E);        // [256]
    ushortT* Wt0    = (ushortT*)(stats + 256);   // [128*256]
    ushortT* WtP    = Wt0 + 128 * 256;           // [128*256]
    ushortT* Wt1    = WtP + 128 * 256;           // [128*128]
    ushortT* WtH    = Wt1 + 128 * 128;           // [48*128]
    int*     bsum   = (int*)(WtH + 48 * 128);    // [256]
    int*     boff   = bsum + 256;                // [256]

    int gE = (E + 255) / 256;
    int nb = (N + 255) / 256;
    int gRows = (N + 63) / 64;
    int gAgg = (N + 3) / 4;
    int gNH2 = (int)((NH / 4 + 255) / 256);      // uint2 granularity

    // CSR build + weight prep
    hipMemsetAsync(cnt, 0, (size_t)N * sizeof(int), stream);
    prep_weights<<<128, 256, 0, stream>>>(W0, pW, W1, hW, Wt0, WtP, Wt1, WtH);
    count_kernel<<<gE, 256, 0, stream>>>(ei, E, cnt);
    scan_block_sum<<<nb, 256, 0, stream>>>(cnt, bsum, dis, N);
    scan_tops<<<1, 256, 0, stream>>>(bsum, boff, &rowptr[N], nb);
    scan_final<<<nb, 256, 0, stream>>>(cnt, boff, rowptr, cursor, N);
    fill_kernel<<<gE, 256, 0, stream>>>(ei, E, cursor, eidx);

    // block 0
    mgemm<IN_DIM, true, false><<<gRows, 256, 0, stream>>>(x, nullptr, Wt0, WtP, pb, hb16, projb, N);
    aggregate_bf<<<gAgg, 256, 0, stream>>>(hb16, rowptr, eidx, dis, aggb, N);
    hipMemsetAsync(stats, 0, 256 * sizeof(float), stream);
    stats_bf<<<256, 256, 0, stream>>>((const unsigned*)aggb, (int)(NH / 2), stats);
    bn_relu_add_v3<<<gNH2, 256, 0, stream>>>((const uint2*)aggb, stats, g0, be0,
                                             (const uint2*)projb, (uint2*)x1b, N);

    // block 1
    mgemm<H, false, true><<<gRows, 256, 0, stream>>>(nullptr, x1b, Wt1, nullptr, nullptr, hb16, nullptr, N);
    aggregate_bf<<<gAgg, 256, 0, stream>>>(hb16, rowptr, eidx, dis, aggb, N);
    hipMemsetAsync(stats, 0, 256 * sizeof(float), stream);
    stats_bf<<<256, 256, 0, stream>>>((const unsigned*)aggb, (int)(NH / 2), stats);

    // head (x2 computed inline)
    head_fused<<<gRows, 256, 0, stream>>>((const uint4*)aggb, (const uint4*)x1b, stats, g1, be1,
                                          WtH, hb, out, N);
}

// Round 5
// 274.229 us; speedup vs baseline: 2.2849x; 1.0191x over previous
//
#include <hip/hip_runtime.h>

#define H 128
#define IN_DIM 256
#define OUT_DIM 40
#define EPS 1e-5f

typedef unsigned short ushortT;
typedef __attribute__((ext_vector_type(8))) short bf16x8;
typedef __attribute__((ext_vector_type(4))) float f32x4;

static __device__ __forceinline__ ushortT f2bf(float f) {
    union { float f; unsigned u; } v; v.f = f;
    unsigned r = v.u + 0x7FFF + ((v.u >> 16) & 1);   // RNE
    return (ushortT)(r >> 16);
}
static __device__ __forceinline__ unsigned pk2(float a, float b) {
    return (unsigned)f2bf(a) | ((unsigned)f2bf(b) << 16);
}
static __device__ __forceinline__ float bflo(unsigned v) {
    union { unsigned u; float f; } t; t.u = v << 16; return t.f;
}
static __device__ __forceinline__ float bfhi(unsigned v) {
    union { unsigned u; float f; } t; t.u = v & 0xFFFF0000u; return t.f;
}

// ---------------- CSR build ----------------

__global__ __launch_bounds__(256) void count_kernel(const int* __restrict__ ei, int E, int* __restrict__ cnt) {
    int e = blockIdx.x * 256 + threadIdx.x;
    if (e < E) atomicAdd(&cnt[ei[E + e]], 1);   // col = target
}

__global__ __launch_bounds__(256) void scan_block_sum(const int* __restrict__ cnt, int* __restrict__ bsum,
                                                      float* __restrict__ dis, int N) {
    __shared__ int s[256];
    int i = blockIdx.x * 256 + threadIdx.x;
    int v = (i < N) ? cnt[i] : 0;
    if (i < N) dis[i] = rsqrtf((float)v + 2.0f);       // improved=True: +2 self loop
    s[threadIdx.x] = v;
    __syncthreads();
    for (int o = 128; o > 0; o >>= 1) {
        if (threadIdx.x < o) s[threadIdx.x] += s[threadIdx.x + o];
        __syncthreads();
    }
    if (threadIdx.x == 0) bsum[blockIdx.x] = s[0];
}

__global__ void scan_tops(const int* __restrict__ bsum, int* __restrict__ boff, int* __restrict__ rowptrN, int nb) {
    __shared__ int s[256];
    int t = threadIdx.x;
    int v = (t < nb) ? bsum[t] : 0;
    s[t] = v;
    __syncthreads();
    for (int o = 1; o < 256; o <<= 1) {
        int u = (t >= o) ? s[t - o] : 0;
        __syncthreads();
        s[t] += u;
        __syncthreads();
    }
    if (t < nb) boff[t] = s[t] - v;
    if (t == 255) *rowptrN = s[255];
}

__global__ __launch_bounds__(256) void scan_final(const int* __restrict__ cnt, const int* __restrict__ boff,
                                                  int* __restrict__ rowptr, int* __restrict__ cursor, int N) {
    __shared__ int s[256];
    int t = threadIdx.x;
    int i = blockIdx.x * 256 + t;
    int v = (i < N) ? cnt[i] : 0;
    s[t] = v;
    __syncthreads();
    for (int o = 1; o < 256; o <<= 1) {
        int u = (t >= o) ? s[t - o] : 0;
        __syncthreads();
        s[t] += u;
        __syncthreads();
    }
    if (i < N) {
        int e = boff[blockIdx.x] + s[t] - v;
        rowptr[i] = e;
        cursor[i] = e;
    }
}

// XCD-partitioned fill: block handles targets in window (blockIdx&7); scatter region stays in one L2.
__global__ __launch_bounds__(256) void fill_xcd(const int* __restrict__ ei, int E, int nper,
                                                int* __restrict__ cursor, int* __restrict__ eidx) {
    int xcd = blockIdx.x & 7;
    int nchunk = gridDim.x >> 3;
    int chunk = blockIdx.x >> 3;
    int csz = (E + nchunk - 1) / nchunk;
    int beg = chunk * csz;
    int end = min(E, beg + csz);
    for (int e = beg + (int)threadIdx.x; e < end; e += 256) {
        int c = ei[E + e];
        if (c / nper == xcd) {
            int slot = atomicAdd(&cursor[c], 1);
            eidx[slot] = ei[e];
        }
    }
}

// ---------------- weight prep: transpose + bf16 ----------------

__global__ __launch_bounds__(256) void prep_weights(const float* __restrict__ W0, const float* __restrict__ pW,
                                                    const float* __restrict__ W1, const float* __restrict__ hW,
                                                    ushortT* __restrict__ Wt0, ushortT* __restrict__ WtP,
                                                    ushortT* __restrict__ Wt1, ushortT* __restrict__ WtH) {
    int i = blockIdx.x * 256 + threadIdx.x;
    if (i < 32768) { int n = i >> 8, k = i & 255; Wt0[i] = f2bf(W0[k * 128 + n]); WtP[i] = f2bf(pW[k * 128 + n]); }
    if (i < 16384) { int n = i >> 7, k = i & 127; Wt1[i] = f2bf(W1[k * 128 + n]); }
    if (i < 6144)  { int n = i >> 7, k = i & 127; WtH[i] = (n < OUT_DIM) ? f2bf(hW[k * OUT_DIM + n]) : (ushortT)0; }
}

// ---------------- GEMM0: dual (h = x@W0, proj = x@pW + pb), K=256, one barrier, B in regs ----------------
// 512 threads (8 waves). BM=64. waves 0-3: W0 -> Oh; waves 4-7: pW + pb -> Op. wave col range = (w&3)*32.

__global__ __launch_bounds__(512) void mgemm0(const float* __restrict__ X,
                                              const ushortT* __restrict__ Wt0,
                                              const ushortT* __restrict__ WtP,
                                              const float* __restrict__ pb,
                                              ushortT* __restrict__ Oh,
                                              ushortT* __restrict__ Op,
                                              int N) {
    __shared__ __align__(16) ushortT As[64][264];     // stride 264 shorts = 528B: 16B-aligned, 2-way max
    int tid = threadIdx.x;
    int brow = blockIdx.x * 64;

    // stage A: 64 rows x 256 f32 -> bf16, coalesced (4096 float4, 8/thread)
#pragma unroll
    for (int i = 0; i < 8; ++i) {
        int idx = i * 512 + tid;
        int row = idx >> 6, c4 = idx & 63;
        int gr = brow + row;
        float4 v = make_float4(0.f, 0.f, 0.f, 0.f);
        if (gr < N) v = *(const float4*)&X[(size_t)gr * IN_DIM + c4 * 4];
        uint2 p;
        p.x = pk2(v.x, v.y);
        p.y = pk2(v.z, v.w);
        *(uint2*)&As[row][c4 * 4] = p;
    }
    __syncthreads();

    int w = tid >> 6, lane = tid & 63;
    int lm = lane & 15, lk = lane >> 4;
    int mat = w >> 2;
    int colbase = (w & 3) * 32;
    const ushortT* Wt = mat ? WtP : Wt0;

    f32x4 acc[4][2];
#pragma unroll
    for (int mt = 0; mt < 4; ++mt)
#pragma unroll
        for (int nt = 0; nt < 2; ++nt) acc[mt][nt] = (f32x4)0.f;

#pragma unroll
    for (int kc = 0; kc < 2; ++kc) {                   // two 128-wide K chunks
        bf16x8 breg[2][4];
#pragma unroll
        for (int nt = 0; nt < 2; ++nt)
#pragma unroll
            for (int ks = 0; ks < 4; ++ks)
                breg[nt][ks] = *(const bf16x8*)&Wt[(size_t)(colbase + nt * 16 + lm) * IN_DIM + kc * 128 + ks * 32 + lk * 8];
#pragma unroll
        for (int ks = 0; ks < 4; ++ks) {
            bf16x8 af[4];
#pragma unroll
            for (int mt = 0; mt < 4; ++mt)
                af[mt] = *(const bf16x8*)&As[mt * 16 + lm][kc * 128 + ks * 32 + lk * 8];
#pragma unroll
            for (int nt = 0; nt < 2; ++nt)
#pragma unroll
                for (int mt = 0; mt < 4; ++mt)
                    acc[mt][nt] = __builtin_amdgcn_mfma_f32_16x16x32_bf16(af[mt], breg[nt][ks], acc[mt][nt], 0, 0, 0);
        }
    }

    float bb[2] = {0.f, 0.f};
    if (mat) {
        bb[0] = pb[colbase + lm];
        bb[1] = pb[colbase + 16 + lm];
    }
    ushortT* O = mat ? Op : Oh;
#pragma unroll
    for (int mt = 0; mt < 4; ++mt)
#pragma unroll
        for (int nt = 0; nt < 2; ++nt) {
            int col = colbase + nt * 16 + lm;
#pragma unroll
            for (int j = 0; j < 4; ++j) {
                int r = brow + mt * 16 + lk * 4 + j;
                if (r < N) O[(size_t)r * 128 + col] = f2bf(acc[mt][nt][j] + bb[nt]);
            }
        }
}

// ---------------- GEMM1: h = x1 @ W1, K=128, bf16 in, one barrier, B in regs ----------------
// 512 threads (8 waves). BM=128. wave w: rows (w>>2)*64.., cols (w&3)*32.

__global__ __launch_bounds__(512) void mgemm1(const ushortT* __restrict__ Xb,
                                              const ushortT* __restrict__ Wt1,
                                              ushortT* __restrict__ O,
                                              int N) {
    __shared__ __align__(16) ushortT As[128][136];    // stride 272B: 16B-aligned, 2-way max
    int tid = threadIdx.x;
    int brow = blockIdx.x * 128;

    // stage A: 128 rows x 128 bf16 (2048 uint4, 4/thread)
#pragma unroll
    for (int i = 0; i < 4; ++i) {
        int idx = i * 512 + tid;
        int row = idx >> 4, q = idx & 15;
        int gr = brow + row;
        uint4 v = make_uint4(0u, 0u, 0u, 0u);
        if (gr < N) v = *(const uint4*)&Xb[(size_t)gr * H + q * 8];
        *(uint4*)&As[row][q * 8] = v;
    }
    __syncthreads();

    int w = tid >> 6, lane = tid & 63;
    int lm = lane & 15, lk = lane >> 4;
    int rh = (w >> 2) * 64;
    int colbase = (w & 3) * 32;

    bf16x8 breg[2][4];
#pragma unroll
    for (int nt = 0; nt < 2; ++nt)
#pragma unroll
        for (int ks = 0; ks < 4; ++ks)
            breg[nt][ks] = *(const bf16x8*)&Wt1[(size_t)(colbase + nt * 16 + lm) * H + ks * 32 + lk * 8];

    f32x4 acc[4][2];
#pragma unroll
    for (int mt = 0; mt < 4; ++mt)
#pragma unroll
        for (int nt = 0; nt < 2; ++nt) acc[mt][nt] = (f32x4)0.f;

#pragma unroll
    for (int ks = 0; ks < 4; ++ks) {
        bf16x8 af[4];
#pragma unroll
        for (int mt = 0; mt < 4; ++mt)
            af[mt] = *(const bf16x8*)&As[rh + mt * 16 + lm][ks * 32 + lk * 8];
#pragma unroll
        for (int nt = 0; nt < 2; ++nt)
#pragma unroll
            for (int mt = 0; mt < 4; ++mt)
                acc[mt][nt] = __builtin_amdgcn_mfma_f32_16x16x32_bf16(af[mt], breg[nt][ks], acc[mt][nt], 0, 0, 0);
    }

#pragma unroll
    for (int mt = 0; mt < 4; ++mt)
#pragma unroll
        for (int nt = 0; nt < 2; ++nt) {
            int col = colbase + nt * 16 + lm;
#pragma unroll
            for (int j = 0; j < 4; ++j) {
                int r = brow + rh + mt * 16 + lk * 4 + j;
                if (r < N) O[(size_t)r * 128 + col] = f2bf(acc[mt][nt][j]);
            }
        }
}

// ---------------- aggregation: one wave per node, bf16 gather, fp32 accumulate, bf16 out ----------------

__global__ __launch_bounds__(256) void aggregate_bf(const ushortT* __restrict__ h,
                                                    const int* __restrict__ rowptr,
                                                    const int* __restrict__ eidx,
                                                    const float* __restrict__ dis,
                                                    ushortT* __restrict__ aggb, int N) {
    int n = blockIdx.x * 4 + (threadIdx.x >> 6);
    int lane = threadIdx.x & 63;
    if (n >= N) return;
    int beg = rowptr[n], end = rowptr[n + 1];
    float dn = dis[n];
    const unsigned* h1 = (const unsigned*)h;     // 2 bf16 per uint
    float a0x = 0.f, a0y = 0.f, a1x = 0.f, a1y = 0.f;
    float a2x = 0.f, a2y = 0.f, a3x = 0.f, a3y = 0.f;
    int p = beg;
    for (; p + 3 < end; p += 4) {
        int s0 = eidx[p], s1 = eidx[p + 1], s2 = eidx[p + 2], s3 = eidx[p + 3];
        float n0 = dis[s0] * dn, n1 = dis[s1] * dn, n2 = dis[s2] * dn, n3 = dis[s3] * dn;
        unsigned v0 = h1[(size_t)s0 * 64 + lane];
        unsigned v1 = h1[(size_t)s1 * 64 + lane];
        unsigned v2 = h1[(size_t)s2 * 64 + lane];
        unsigned v3 = h1[(size_t)s3 * 64 + lane];
        a0x = fmaf(n0, bflo(v0), a0x); a0y = fmaf(n0, bfhi(v0), a0y);
        a1x = fmaf(n1, bflo(v1), a1x); a1y = fmaf(n1, bfhi(v1), a1y);
        a2x = fmaf(n2, bflo(v2), a2x); a2y = fmaf(n2, bfhi(v2), a2y);
        a3x = fmaf(n3, bflo(v3), a3x); a3y = fmaf(n3, bfhi(v3), a3y);
    }
    for (; p < end; ++p) {
        int s0 = eidx[p];
        float n0 = dis[s0] * dn;
        unsigned v0 = h1[(size_t)s0 * 64 + lane];
        a0x = fmaf(n0, bflo(v0), a0x); a0y = fmaf(n0, bfhi(v0), a0y);
    }
    {
        unsigned v = h1[(size_t)n * 64 + lane];
        float sw = 2.f * dn * dn;                // self loop, fill=2.0
        a0x = fmaf(sw, bflo(v), a0x); a0y = fmaf(sw, bfhi(v), a0y);
    }
    float rx = (a0x + a1x) + (a2x + a3x);
    float ry = (a0y + a1y) + (a2y + a3y);
    ((unsigned*)aggb)[(size_t)n * 64 + lane] = pk2(rx, ry);
}

// ---------------- BN stats from bf16 (raw sums) ----------------

__global__ __launch_bounds__(256) void stats_bf(const unsigned* __restrict__ v, int totalU,
                                                float* __restrict__ sums) {
    int tid = blockIdx.x * 256 + threadIdx.x;
    int stride = gridDim.x * 256;
    float sx = 0.f, sy = 0.f, qx = 0.f, qy = 0.f;
    for (int i = tid; i < totalU; i += stride) {
        unsigned u = v[i];
        float a = bflo(u), b = bfhi(u);
        sx += a; sy += b;
        qx = fmaf(a, a, qx); qy = fmaf(b, b, qy);
    }
    __shared__ float l0[256], l1[256], l2[256], l3[256];
    int t = threadIdx.x;
    l0[t] = sx; l1[t] = sy; l2[t] = qx; l3[t] = qy;
    __syncthreads();
    if (t < 64) {
        sx = (l0[t] + l0[t + 64]) + (l0[t + 128] + l0[t + 192]);
        sy = (l1[t] + l1[t + 64]) + (l1[t + 128] + l1[t + 192]);
        qx = (l2[t] + l2[t + 64]) + (l2[t + 128] + l2[t + 192]);
        qy = (l3[t] + l3[t + 64]) + (l3[t + 128] + l3[t + 192]);
        atomicAdd(&sums[2 * t], sx);
        atomicAdd(&sums[2 * t + 1], sy);
        atomicAdd(&sums[128 + 2 * t], qx);
        atomicAdd(&sums[128 + 2 * t + 1], qy);
    }
}

// ---------------- x1 = relu(bn(agg)) + proj, all bf16 ----------------

__global__ __launch_bounds__(256) void bn_relu_add_v3(const uint2* __restrict__ aggb,
                                                      const float* __restrict__ stats,
                                                      const float* __restrict__ g,
                                                      const float* __restrict__ be,
                                                      const uint2* __restrict__ projb,
                                                      uint2* __restrict__ x1b, int N) {
    __shared__ float sc[128], sh[128];
    int t = threadIdx.x;
    if (t < 128) {
        float mean = stats[t] / (float)N;
        float var = stats[128 + t] / (float)N - mean * mean;
        float inv = rsqrtf(var + EPS);
        float s = g[t] * inv;
        sc[t] = s;
        sh[t] = be[t] - mean * s;
    }
    __syncthreads();
    size_t i2 = (size_t)blockIdx.x * 256 + t;
    size_t total2 = (size_t)N * 32;
    if (i2 >= total2) return;
    int ch = (int)(i2 & 31) * 4;
    uint2 a = aggb[i2];
    uint2 d = projb[i2];
    float v0 = fmaxf(fmaf(bflo(a.x), sc[ch + 0], sh[ch + 0]), 0.f) + bflo(d.x);
    float v1 = fmaxf(fmaf(bfhi(a.x), sc[ch + 1], sh[ch + 1]), 0.f) + bfhi(d.x);
    float v2 = fmaxf(fmaf(bflo(a.y), sc[ch + 2], sh[ch + 2]), 0.f) + bflo(d.y);
    float v3 = fmaxf(fmaf(bfhi(a.y), sc[ch + 3], sh[ch + 3]), 0.f) + bfhi(d.y);
    uint2 r;
    r.x = pk2(v0, v1);
    r.y = pk2(v2, v3);
    x1b[i2] = r;
}

// ---------------- head: out = (relu(bn(agg)) + x1) @ hW + hb, x2 inline, coalesced staging ----------------

__global__ __launch_bounds__(256) void head_fused(const uint4* __restrict__ aggb,
                                                  const uint4* __restrict__ x1b,
                                                  const float* __restrict__ stats,
                                                  const float* __restrict__ g,
                                                  const float* __restrict__ be,
                                                  const ushortT* __restrict__ WtH,
                                                  const float* __restrict__ hb,
                                                  float* __restrict__ out, int N) {
    __shared__ __align__(16) ushortT As[64][136];
    __shared__ __align__(16) ushortT Bs[48][136];
    __shared__ float sc[128], sh[128];

    int tid = threadIdx.x;
    int brow = blockIdx.x * 64;
    int w = tid >> 6, lane = tid & 63;
    int lm = lane & 15, lk = lane >> 4;

    if (tid < 128) {
        float mean = stats[tid] / (float)N;
        float var = stats[128 + tid] / (float)N - mean * mean;
        float inv = rsqrtf(var + EPS);
        float s = g[tid] * inv;
        sc[tid] = s;
        sh[tid] = be[tid] - mean * s;
    }
    if (tid < 192) {
        int row = tid >> 2, q = tid & 3;
        const uint4* src = (const uint4*)&WtH[(size_t)row * H + q * 32];
        uint4 a = src[0], b = src[1], c = src[2], d = src[3];
        uint4* dst = (uint4*)&Bs[row][q * 32];
        dst[0] = a; dst[1] = b; dst[2] = c; dst[3] = d;
    }
    __syncthreads();
#pragma unroll
    for (int k = 0; k < 4; ++k) {
        int idx = k * 256 + tid;
        int row = idx >> 4, colq = idx & 15;
        int gr = brow + row;
        uint4 a = make_uint4(0u, 0u, 0u, 0u), x = a;
        if (gr < N) {
            size_t gidx = (size_t)brow * 16 + idx;
            a = aggb[gidx];
            x = x1b[gidx];
        }
        int ch = colq * 8;
        float v0 = fmaxf(fmaf(bflo(a.x), sc[ch + 0], sh[ch + 0]), 0.f) + bflo(x.x);
        float v1 = fmaxf(fmaf(bfhi(a.x), sc[ch + 1], sh[ch + 1]), 0.f) + bfhi(x.x);
        float v2 = fmaxf(fmaf(bflo(a.y), sc[ch + 2], sh[ch + 2]), 0.f) + bflo(x.y);
        float v3 = fmaxf(fmaf(bfhi(a.y), sc[ch + 3], sh[ch + 3]), 0.f) + bfhi(x.y);
        float v4 = fmaxf(fmaf(bflo(a.z), sc[ch + 4], sh[ch + 4]), 0.f) + bflo(x.z);
        float v5 = fmaxf(fmaf(bfhi(a.z), sc[ch + 5], sh[ch + 5]), 0.f) + bfhi(x.z);
        float v6 = fmaxf(fmaf(bflo(a.w), sc[ch + 6], sh[ch + 6]), 0.f) + bflo(x.w);
        float v7 = fmaxf(fmaf(bfhi(a.w), sc[ch + 7], sh[ch + 7]), 0.f) + bfhi(x.w);
        uint4 pv;
        pv.x = pk2(v0, v1);
        pv.y = pk2(v2, v3);
        pv.z = pk2(v4, v5);
        pv.w = pk2(v6, v7);
        *(uint4*)&As[row][colq * 8] = pv;
    }
    __syncthreads();

    f32x4 acc[3];
#pragma unroll
    for (int nt = 0; nt < 3; ++nt) acc[nt] = (f32x4)0.f;
#pragma unroll
    for (int ks = 0; ks < 4; ++ks) {
        bf16x8 a = *(const bf16x8*)&As[w * 16 + lm][ks * 32 + lk * 8];
#pragma unroll
        for (int nt = 0; nt < 3; ++nt) {
            bf16x8 b = *(const bf16x8*)&Bs[nt * 16 + lm][ks * 32 + lk * 8];
            acc[nt] = __builtin_amdgcn_mfma_f32_16x16x32_bf16(a, b, acc[nt], 0, 0, 0);
        }
    }
#pragma unroll
    for (int nt = 0; nt < 3; ++nt) {
        int col = nt * 16 + lm;
        if (col < OUT_DIM) {
            float bbv = hb[col];
#pragma unroll
            for (int j = 0; j < 4; ++j) {
                int r = brow + w * 16 + lk * 4 + j;
                if (r < N) out[(size_t)r * OUT_DIM + col] = acc[nt][j] + bbv;
            }
        }
    }
}

// ---------------- launch ----------------

extern "C" void kernel_launch(void* const* d_in, const int* in_sizes, int n_in,
                              void* d_out, int out_size, void* d_ws, size_t ws_size,
                              hipStream_t stream) {
    const float* x   = (const float*)d_in[0];
    const int*   ei  = (const int*)d_in[1];
    const float* W0  = (const float*)d_in[2];
    // d_in[3] = b0: cancels in BatchNorm
    const float* g0  = (const float*)d_in[4];
    const float* be0 = (const float*)d_in[5];
    const float* pW  = (const float*)d_in[6];
    const float* pb  = (const float*)d_in[7];
    const float* W1  = (const float*)d_in[8];
    // d_in[9] = b1: cancels in BatchNorm
    const float* g1  = (const float*)d_in[10];
    const float* be1 = (const float*)d_in[11];
    const float* hW  = (const float*)d_in[12];
    const float* hb  = (const float*)d_in[13];
    float* out = (float*)d_out;

    int N = in_sizes[0] / IN_DIM;
    int E = in_sizes[1] / 2;
    size_t NH = (size_t)N * H;

    // workspace layout (all bf16 intermediates)
    ushortT* hb16   = (ushortT*)d_ws;            // [N,128] conv input h
    ushortT* aggb   = hb16 + NH;                 // [N,128] aggregated
    ushortT* projb  = aggb + NH;                 // [N,128] proj (block0)
    ushortT* x1b    = projb + NH;                // [N,128] x1
    float*   dis    = (float*)(x1b + NH);        // [N]
    int*     cnt    = (int*)(dis + N);           // [N]
    int*     rowptr = cnt + N;                   // [N+1]
    int*     cursor = rowptr + (N + 1);          // [N]
    int*     eidx   = cursor + N;                // [E]
    float*   stats  = (float*)(eidx + E);        // [256]
    ushortT* Wt0    = (ushortT*)(stats + 256);   // [128*256]
    ushortT* WtP    = Wt0 + 128 * 256;           // [128*256]
    ushortT* Wt1    = WtP + 128 * 256;           // [128*128]
    ushortT* WtH    = Wt1 + 128 * 128;           // [48*128]
    int*     bsum   = (int*)(WtH + 48 * 128);    // [256]
    int*     boff   = bsum + 256;                // [256]

    int gE = (E + 255) / 256;
    int nb = (N + 255) / 256;
    int g64 = (N + 63) / 64;
    int g128 = (N + 127) / 128;
    int gAgg = (N + 3) / 4;
    int gNH2 = (int)((NH / 4 + 255) / 256);      // uint2 granularity

    // CSR build + weight prep
    hipMemsetAsync(cnt, 0, (size_t)N * sizeof(int), stream);
    prep_weights<<<128, 256, 0, stream>>>(W0, pW, W1, hW, Wt0, WtP, Wt1, WtH);
    count_kernel<<<gE, 256, 0, stream>>>(ei, E, cnt);
    scan_block_sum<<<nb, 256, 0, stream>>>(cnt, bsum, dis, N);
    scan_tops<<<1, 256, 0, stream>>>(bsum, boff, &rowptr[N], nb);
    scan_final<<<nb, 256, 0, stream>>>(cnt, boff, rowptr, cursor, N);
    fill_xcd<<<2048, 256, 0, stream>>>(ei, E, (N + 7) / 8, cursor, eidx);

    // block 0
    mgemm0<<<g64, 512, 0, stream>>>(x, Wt0, WtP, pb, hb16, projb, N);
    aggregate_bf<<<gAgg, 256, 0, stream>>>(hb16, rowptr, eidx, dis, aggb, N);
    hipMemsetAsync(stats, 0, 256 * sizeof(float), stream);
    stats_bf<<<256, 256, 0, stream>>>((const unsigned*)aggb, (int)(NH / 2), stats);
    bn_relu_add_v3<<<gNH2, 256, 0, stream>>>((const uint2*)aggb, stats, g0, be0,
                                             (const uint2*)projb, (uint2*)x1b, N);

    // block 1
    mgemm1<<<g128, 512, 0, stream>>>(x1b, Wt1, hb16, N);
    aggregate_bf<<<gAgg, 256, 0, stream>>>(hb16, rowptr, eidx, dis, aggb, N);
    hipMemsetAsync(stats, 0, 256 * sizeof(float), stream);
    stats_bf<<<256, 256, 0, stream>>>((const unsigned*)aggb, (int)(NH / 2), stats);

    // head (x2 computed inline)
    head_fused<<<g64, 256, 0, stream>>>((const uint4*)aggb, (const uint4*)x1b, stats, g1, be1,
                                        WtH, hb, out, N);
}

// Round 6
// 262.343 us; speedup vs baseline: 2.3885x; 1.0453x over previous
//
#include <hip/hip_runtime.h>

#define H 128
#define IN_DIM 256
#define OUT_DIM 40
#define EPS 1e-5f

typedef unsigned short ushortT;
typedef __attribute__((ext_vector_type(8))) short bf16x8;
typedef __attribute__((ext_vector_type(4))) float f32x4;

static __device__ __forceinline__ ushortT f2bf(float f) {
    union { float f; unsigned u; } v; v.f = f;
    unsigned r = v.u + 0x7FFF + ((v.u >> 16) & 1);   // RNE
    return (ushortT)(r >> 16);
}
static __device__ __forceinline__ unsigned pk2(float a, float b) {
    return (unsigned)f2bf(a) | ((unsigned)f2bf(b) << 16);
}
static __device__ __forceinline__ float bflo(unsigned v) {
    union { unsigned u; float f; } t; t.u = v << 16; return t.f;
}
static __device__ __forceinline__ float bfhi(unsigned v) {
    union { unsigned u; float f; } t; t.u = v & 0xFFFF0000u; return t.f;
}

// ---------------- CSR build ----------------

__global__ __launch_bounds__(256) void count_kernel(const int* __restrict__ ei, int E, int* __restrict__ cnt) {
    int e = blockIdx.x * 256 + threadIdx.x;
    if (e < E) atomicAdd(&cnt[ei[E + e]], 1);   // col = target
}

__global__ __launch_bounds__(256) void scan_block_sum(const int* __restrict__ cnt, int* __restrict__ bsum,
                                                      float* __restrict__ dis, int N) {
    __shared__ int s[256];
    int i = blockIdx.x * 256 + threadIdx.x;
    int v = (i < N) ? cnt[i] : 0;
    if (i < N) dis[i] = rsqrtf((float)v + 2.0f);       // improved=True: +2 self loop
    s[threadIdx.x] = v;
    __syncthreads();
    for (int o = 128; o > 0; o >>= 1) {
        if (threadIdx.x < o) s[threadIdx.x] += s[threadIdx.x + o];
        __syncthreads();
    }
    if (threadIdx.x == 0) bsum[blockIdx.x] = s[0];
}

__global__ void scan_tops(const int* __restrict__ bsum, int* __restrict__ boff, int* __restrict__ rowptrN, int nb) {
    __shared__ int s[256];
    int t = threadIdx.x;
    int v = (t < nb) ? bsum[t] : 0;
    s[t] = v;
    __syncthreads();
    for (int o = 1; o < 256; o <<= 1) {
        int u = (t >= o) ? s[t - o] : 0;
        __syncthreads();
        s[t] += u;
        __syncthreads();
    }
    if (t < nb) boff[t] = s[t] - v;
    if (t == 255) *rowptrN = s[255];
}

__global__ __launch_bounds__(256) void scan_final(const int* __restrict__ cnt, const int* __restrict__ boff,
                                                  int* __restrict__ rowptr, int* __restrict__ cursor, int N) {
    __shared__ int s[256];
    int t = threadIdx.x;
    int i = blockIdx.x * 256 + t;
    int v = (i < N) ? cnt[i] : 0;
    s[t] = v;
    __syncthreads();
    for (int o = 1; o < 256; o <<= 1) {
        int u = (t >= o) ? s[t - o] : 0;
        __syncthreads();
        s[t] += u;
        __syncthreads();
    }
    if (i < N) {
        int e = boff[blockIdx.x] + s[t] - v;
        rowptr[i] = e;
        cursor[i] = e;
    }
}

// XCD-partitioned fill: block handles targets in window (blockIdx&7); scatter region stays in one L2.
__global__ __launch_bounds__(256) void fill_xcd(const int* __restrict__ ei, int E, int nper,
                                                int* __restrict__ cursor, int* __restrict__ eidx) {
    int xcd = blockIdx.x & 7;
    int nchunk = gridDim.x >> 3;
    int chunk = blockIdx.x >> 3;
    int csz = (E + nchunk - 1) / nchunk;
    int beg = chunk * csz;
    int end = min(E, beg + csz);
    for (int e = beg + (int)threadIdx.x; e < end; e += 256) {
        int c = ei[E + e];
        if (c / nper == xcd) {
            int slot = atomicAdd(&cursor[c], 1);
            eidx[slot] = ei[e];
        }
    }
}

// ---------------- weight prep: transpose + bf16 ----------------

__global__ __launch_bounds__(256) void prep_weights(const float* __restrict__ W0, const float* __restrict__ pW,
                                                    const float* __restrict__ W1, const float* __restrict__ hW,
                                                    ushortT* __restrict__ Wt0, ushortT* __restrict__ WtP,
                                                    ushortT* __restrict__ Wt1, ushortT* __restrict__ WtH) {
    int i = blockIdx.x * 256 + threadIdx.x;
    if (i < 32768) { int n = i >> 8, k = i & 255; Wt0[i] = f2bf(W0[k * 128 + n]); WtP[i] = f2bf(pW[k * 128 + n]); }
    if (i < 16384) { int n = i >> 7, k = i & 127; Wt1[i] = f2bf(W1[k * 128 + n]); }
    if (i < 6144)  { int n = i >> 7, k = i & 127; WtH[i] = (n < OUT_DIM) ? f2bf(hW[k * OUT_DIM + n]) : (ushortT)0; }
}

// ---------------- GEMM0: dual (h = x@W0, proj = x@pW + pb), K=256, B in regs, LDS epilogue ----------------
// 512 threads (8 waves). BM=64. waves 0-3: W0 -> Oh; waves 4-7: pW + pb -> Op. wave col range = (w&3)*32.
// Shared buffer S (17408 shorts): A as [64][264] during compute, C as [2][64][136] during epilogue.

__global__ __launch_bounds__(512) void mgemm0(const float* __restrict__ X,
                                              const ushortT* __restrict__ Wt0,
                                              const ushortT* __restrict__ WtP,
                                              const float* __restrict__ pb,
                                              ushortT* __restrict__ Oh,
                                              ushortT* __restrict__ Op,
                                              int N) {
    __shared__ __align__(16) ushortT S[17408];
    int tid = threadIdx.x;
    int brow = blockIdx.x * 64;

    // stage A: 64 rows x 256 f32 -> bf16, coalesced (4096 float4, 8/thread). A stride 264 shorts.
#pragma unroll
    for (int i = 0; i < 8; ++i) {
        int idx = i * 512 + tid;
        int row = idx >> 6, c4 = idx & 63;
        int gr = brow + row;
        float4 v = make_float4(0.f, 0.f, 0.f, 0.f);
        if (gr < N) v = *(const float4*)&X[(size_t)gr * IN_DIM + c4 * 4];
        uint2 p;
        p.x = pk2(v.x, v.y);
        p.y = pk2(v.z, v.w);
        *(uint2*)&S[row * 264 + c4 * 4] = p;
    }
    __syncthreads();

    int w = tid >> 6, lane = tid & 63;
    int lm = lane & 15, lk = lane >> 4;
    int mat = w >> 2;
    int colbase = (w & 3) * 32;
    const ushortT* Wt = mat ? WtP : Wt0;

    f32x4 acc[4][2];
#pragma unroll
    for (int mt = 0; mt < 4; ++mt)
#pragma unroll
        for (int nt = 0; nt < 2; ++nt) acc[mt][nt] = (f32x4)0.f;

#pragma unroll
    for (int kc = 0; kc < 2; ++kc) {                   // two 128-wide K chunks
        bf16x8 breg[2][4];
#pragma unroll
        for (int nt = 0; nt < 2; ++nt)
#pragma unroll
            for (int ks = 0; ks < 4; ++ks)
                breg[nt][ks] = *(const bf16x8*)&Wt[(size_t)(colbase + nt * 16 + lm) * IN_DIM + kc * 128 + ks * 32 + lk * 8];
#pragma unroll
        for (int ks = 0; ks < 4; ++ks) {
            bf16x8 af[4];
#pragma unroll
            for (int mt = 0; mt < 4; ++mt)
                af[mt] = *(const bf16x8*)&S[(mt * 16 + lm) * 264 + kc * 128 + ks * 32 + lk * 8];
#pragma unroll
            for (int nt = 0; nt < 2; ++nt)
#pragma unroll
                for (int mt = 0; mt < 4; ++mt)
                    acc[mt][nt] = __builtin_amdgcn_mfma_f32_16x16x32_bf16(af[mt], breg[nt][ks], acc[mt][nt], 0, 0, 0);
        }
    }

    float bb[2] = {0.f, 0.f};
    if (mat) {
        bb[0] = pb[colbase + lm];
        bb[1] = pb[colbase + 16 + lm];
    }
    __syncthreads();                                   // all A reads done; reuse S for C
    // C staging: [mat][row][col], stride 136 shorts (272B, 16B-aligned)
#pragma unroll
    for (int mt = 0; mt < 4; ++mt)
#pragma unroll
        for (int nt = 0; nt < 2; ++nt) {
            int col = colbase + nt * 16 + lm;
#pragma unroll
            for (int j = 0; j < 4; ++j) {
                int row = mt * 16 + lk * 4 + j;
                S[mat * 8704 + row * 136 + col] = f2bf(acc[mt][nt][j] + bb[nt]);
            }
        }
    __syncthreads();
    // coalesced stores: 2048 uint4 (2 matrices x 64 rows x 16 uint4), 4 per thread
#pragma unroll
    for (int i = 0; i < 4; ++i) {
        int idx = i * 512 + tid;
        int m2 = idx >> 10;
        int rem = idx & 1023;
        int row = rem >> 4, colq = rem & 15;
        int gr = brow + row;
        if (gr < N) {
            uint4 v = *(const uint4*)&S[m2 * 8704 + row * 136 + colq * 8];
            ushortT* O = m2 ? Op : Oh;
            *(uint4*)&O[(size_t)gr * 128 + colq * 8] = v;
        }
    }
}

// ---------------- GEMM1 fused: x1 = relu(bn(agg)) + proj (written out), h = x1 @ W1, LDS epilogue ----------------
// 512 threads (8 waves). BM=128. wave w: rows (w>>2)*64.., cols (w&3)*32. A/C stride 136 shorts.

__global__ __launch_bounds__(512) void mgemm1_fused(const uint4* __restrict__ aggb,
                                                    const uint4* __restrict__ projb,
                                                    const float* __restrict__ stats,
                                                    const float* __restrict__ g,
                                                    const float* __restrict__ be,
                                                    const ushortT* __restrict__ Wt1,
                                                    ushortT* __restrict__ O,
                                                    uint4* __restrict__ x1b,
                                                    int N) {
    __shared__ __align__(16) ushortT S[17408];
    __shared__ float sc[128], sh[128];
    int tid = threadIdx.x;
    int brow = blockIdx.x * 128;

    if (tid < 128) {
        float mean = stats[tid] / (float)N;
        float var = stats[128 + tid] / (float)N - mean * mean;
        float inv = rsqrtf(var + EPS);
        float s = g[tid] * inv;
        sc[tid] = s;
        sh[tid] = be[tid] - mean * s;
    }
    __syncthreads();

    // stage A = x1: 128 rows x 128 bf16 (2048 uint4, 4/thread); also write x1 to global (coalesced)
#pragma unroll
    for (int i = 0; i < 4; ++i) {
        int idx = i * 512 + tid;
        int row = idx >> 4, q = idx & 15;
        int gr = brow + row;
        uint4 a = make_uint4(0u, 0u, 0u, 0u), p = a;
        if (gr < N) {
            size_t gidx = (size_t)gr * 16 + q;
            a = aggb[gidx];
            p = projb[gidx];
        }
        int ch = q * 8;
        float v0 = fmaxf(fmaf(bflo(a.x), sc[ch + 0], sh[ch + 0]), 0.f) + bflo(p.x);
        float v1 = fmaxf(fmaf(bfhi(a.x), sc[ch + 1], sh[ch + 1]), 0.f) + bfhi(p.x);
        float v2 = fmaxf(fmaf(bflo(a.y), sc[ch + 2], sh[ch + 2]), 0.f) + bflo(p.y);
        float v3 = fmaxf(fmaf(bfhi(a.y), sc[ch + 3], sh[ch + 3]), 0.f) + bfhi(p.y);
        float v4 = fmaxf(fmaf(bflo(a.z), sc[ch + 4], sh[ch + 4]), 0.f) + bflo(p.z);
        float v5 = fmaxf(fmaf(bfhi(a.z), sc[ch + 5], sh[ch + 5]), 0.f) + bfhi(p.z);
        float v6 = fmaxf(fmaf(bflo(a.w), sc[ch + 6], sh[ch + 6]), 0.f) + bflo(p.w);
        float v7 = fmaxf(fmaf(bfhi(a.w), sc[ch + 7], sh[ch + 7]), 0.f) + bfhi(p.w);
        uint4 pv;
        pv.x = pk2(v0, v1);
        pv.y = pk2(v2, v3);
        pv.z = pk2(v4, v5);
        pv.w = pk2(v6, v7);
        *(uint4*)&S[row * 136 + q * 8] = pv;
        if (gr < N) x1b[(size_t)gr * 16 + q] = pv;
    }
    __syncthreads();

    int w = tid >> 6, lane = tid & 63;
    int lm = lane & 15, lk = lane >> 4;
    int rh = (w >> 2) * 64;
    int colbase = (w & 3) * 32;

    bf16x8 breg[2][4];
#pragma unroll
    for (int nt = 0; nt < 2; ++nt)
#pragma unroll
        for (int ks = 0; ks < 4; ++ks)
            breg[nt][ks] = *(const bf16x8*)&Wt1[(size_t)(colbase + nt * 16 + lm) * H + ks * 32 + lk * 8];

    f32x4 acc[4][2];
#pragma unroll
    for (int mt = 0; mt < 4; ++mt)
#pragma unroll
        for (int nt = 0; nt < 2; ++nt) acc[mt][nt] = (f32x4)0.f;

#pragma unroll
    for (int ks = 0; ks < 4; ++ks) {
        bf16x8 af[4];
#pragma unroll
        for (int mt = 0; mt < 4; ++mt)
            af[mt] = *(const bf16x8*)&S[(rh + mt * 16 + lm) * 136 + ks * 32 + lk * 8];
#pragma unroll
        for (int nt = 0; nt < 2; ++nt)
#pragma unroll
            for (int mt = 0; mt < 4; ++mt)
                acc[mt][nt] = __builtin_amdgcn_mfma_f32_16x16x32_bf16(af[mt], breg[nt][ks], acc[mt][nt], 0, 0, 0);
    }

    __syncthreads();                                   // reuse S for C: [128][136]
#pragma unroll
    for (int mt = 0; mt < 4; ++mt)
#pragma unroll
        for (int nt = 0; nt < 2; ++nt) {
            int col = colbase + nt * 16 + lm;
#pragma unroll
            for (int j = 0; j < 4; ++j) {
                int row = rh + mt * 16 + lk * 4 + j;
                S[row * 136 + col] = f2bf(acc[mt][nt][j]);
            }
        }
    __syncthreads();
#pragma unroll
    for (int i = 0; i < 4; ++i) {
        int idx = i * 512 + tid;
        int row = idx >> 4, colq = idx & 15;
        int gr = brow + row;
        if (gr < N) {
            uint4 v = *(const uint4*)&S[row * 136 + colq * 8];
            *(uint4*)&O[(size_t)gr * 128 + colq * 8] = v;
        }
    }
}

// ---------------- aggregation: one wave per node, bf16 gather, fp32 accumulate, bf16 out ----------------

__global__ __launch_bounds__(256) void aggregate_bf(const ushortT* __restrict__ h,
                                                    const int* __restrict__ rowptr,
                                                    const int* __restrict__ eidx,
                                                    const float* __restrict__ dis,
                                                    ushortT* __restrict__ aggb, int N) {
    int n = blockIdx.x * 4 + (threadIdx.x >> 6);
    int lane = threadIdx.x & 63;
    if (n >= N) return;
    int beg = rowptr[n], end = rowptr[n + 1];
    float dn = dis[n];
    const unsigned* h1 = (const unsigned*)h;     // 2 bf16 per uint
    float a0x = 0.f, a0y = 0.f, a1x = 0.f, a1y = 0.f;
    float a2x = 0.f, a2y = 0.f, a3x = 0.f, a3y = 0.f;
    int p = beg;
    for (; p + 3 < end; p += 4) {
        int s0 = eidx[p], s1 = eidx[p + 1], s2 = eidx[p + 2], s3 = eidx[p + 3];
        float n0 = dis[s0] * dn, n1 = dis[s1] * dn, n2 = dis[s2] * dn, n3 = dis[s3] * dn;
        unsigned v0 = h1[(size_t)s0 * 64 + lane];
        unsigned v1 = h1[(size_t)s1 * 64 + lane];
        unsigned v2 = h1[(size_t)s2 * 64 + lane];
        unsigned v3 = h1[(size_t)s3 * 64 + lane];
        a0x = fmaf(n0, bflo(v0), a0x); a0y = fmaf(n0, bfhi(v0), a0y);
        a1x = fmaf(n1, bflo(v1), a1x); a1y = fmaf(n1, bfhi(v1), a1y);
        a2x = fmaf(n2, bflo(v2), a2x); a2y = fmaf(n2, bfhi(v2), a2y);
        a3x = fmaf(n3, bflo(v3), a3x); a3y = fmaf(n3, bfhi(v3), a3y);
    }
    for (; p < end; ++p) {
        int s0 = eidx[p];
        float n0 = dis[s0] * dn;
        unsigned v0 = h1[(size_t)s0 * 64 + lane];
        a0x = fmaf(n0, bflo(v0), a0x); a0y = fmaf(n0, bfhi(v0), a0y);
    }
    {
        unsigned v = h1[(size_t)n * 64 + lane];
        float sw = 2.f * dn * dn;                // self loop, fill=2.0
        a0x = fmaf(sw, bflo(v), a0x); a0y = fmaf(sw, bfhi(v), a0y);
    }
    float rx = (a0x + a1x) + (a2x + a3x);
    float ry = (a0y + a1y) + (a2y + a3y);
    ((unsigned*)aggb)[(size_t)n * 64 + lane] = pk2(rx, ry);
}

// ---------------- BN stats from bf16 (raw sums) ----------------

__global__ __launch_bounds__(256) void stats_bf(const unsigned* __restrict__ v, int totalU,
                                                float* __restrict__ sums) {
    int tid = blockIdx.x * 256 + threadIdx.x;
    int stride = gridDim.x * 256;
    float sx = 0.f, sy = 0.f, qx = 0.f, qy = 0.f;
    for (int i = tid; i < totalU; i += stride) {
        unsigned u = v[i];
        float a = bflo(u), b = bfhi(u);
        sx += a; sy += b;
        qx = fmaf(a, a, qx); qy = fmaf(b, b, qy);
    }
    __shared__ float l0[256], l1[256], l2[256], l3[256];
    int t = threadIdx.x;
    l0[t] = sx; l1[t] = sy; l2[t] = qx; l3[t] = qy;
    __syncthreads();
    if (t < 64) {
        sx = (l0[t] + l0[t + 64]) + (l0[t + 128] + l0[t + 192]);
        sy = (l1[t] + l1[t + 64]) + (l1[t + 128] + l1[t + 192]);
        qx = (l2[t] + l2[t + 64]) + (l2[t + 128] + l2[t + 192]);
        qy = (l3[t] + l3[t + 64]) + (l3[t + 128] + l3[t + 192]);
        atomicAdd(&sums[2 * t], sx);
        atomicAdd(&sums[2 * t + 1], sy);
        atomicAdd(&sums[128 + 2 * t], qx);
        atomicAdd(&sums[128 + 2 * t + 1], qy);
    }
}

// ---------------- head: out = (relu(bn(agg)) + x1) @ hW + hb, x2 inline, coalesced staging ----------------

__global__ __launch_bounds__(256) void head_fused(const uint4* __restrict__ aggb,
                                                  const uint4* __restrict__ x1b,
                                                  const float* __restrict__ stats,
                                                  const float* __restrict__ g,
                                                  const float* __restrict__ be,
                                                  const ushortT* __restrict__ WtH,
                                                  const float* __restrict__ hb,
                                                  float* __restrict__ out, int N) {
    __shared__ __align__(16) ushortT As[64][136];
    __shared__ __align__(16) ushortT Bs[48][136];
    __shared__ float sc[128], sh[128];

    int tid = threadIdx.x;
    int brow = blockIdx.x * 64;
    int w = tid >> 6, lane = tid & 63;
    int lm = lane & 15, lk = lane >> 4;

    if (tid < 128) {
        float mean = stats[tid] / (float)N;
        float var = stats[128 + tid] / (float)N - mean * mean;
        float inv = rsqrtf(var + EPS);
        float s = g[tid] * inv;
        sc[tid] = s;
        sh[tid] = be[tid] - mean * s;
    }
    if (tid < 192) {
        int row = tid >> 2, q = tid & 3;
        const uint4* src = (const uint4*)&WtH[(size_t)row * H + q * 32];
        uint4 a = src[0], b = src[1], c = src[2], d = src[3];
        uint4* dst = (uint4*)&Bs[row][q * 32];
        dst[0] = a; dst[1] = b; dst[2] = c; dst[3] = d;
    }
    __syncthreads();
#pragma unroll
    for (int k = 0; k < 4; ++k) {
        int idx = k * 256 + tid;
        int row = idx >> 4, colq = idx & 15;
        int gr = brow + row;
        uint4 a = make_uint4(0u, 0u, 0u, 0u), x = a;
        if (gr < N) {
            size_t gidx = (size_t)brow * 16 + idx;
            a = aggb[gidx];
            x = x1b[gidx];
        }
        int ch = colq * 8;
        float v0 = fmaxf(fmaf(bflo(a.x), sc[ch + 0], sh[ch + 0]), 0.f) + bflo(x.x);
        float v1 = fmaxf(fmaf(bfhi(a.x), sc[ch + 1], sh[ch + 1]), 0.f) + bfhi(x.x);
        float v2 = fmaxf(fmaf(bflo(a.y), sc[ch + 2], sh[ch + 2]), 0.f) + bflo(x.y);
        float v3 = fmaxf(fmaf(bfhi(a.y), sc[ch + 3], sh[ch + 3]), 0.f) + bfhi(x.y);
        float v4 = fmaxf(fmaf(bflo(a.z), sc[ch + 4], sh[ch + 4]), 0.f) + bflo(x.z);
        float v5 = fmaxf(fmaf(bfhi(a.z), sc[ch + 5], sh[ch + 5]), 0.f) + bfhi(x.z);
        float v6 = fmaxf(fmaf(bflo(a.w), sc[ch + 6], sh[ch + 6]), 0.f) + bflo(x.w);
        float v7 = fmaxf(fmaf(bfhi(a.w), sc[ch + 7], sh[ch + 7]), 0.f) + bfhi(x.w);
        uint4 pv;
        pv.x = pk2(v0, v1);
        pv.y = pk2(v2, v3);
        pv.z = pk2(v4, v5);
        pv.w = pk2(v6, v7);
        *(uint4*)&As[row][colq * 8] = pv;
    }
    __syncthreads();

    f32x4 acc[3];
#pragma unroll
    for (int nt = 0; nt < 3; ++nt) acc[nt] = (f32x4)0.f;
#pragma unroll
    for (int ks = 0; ks < 4; ++ks) {
        bf16x8 a = *(const bf16x8*)&As[w * 16 + lm][ks * 32 + lk * 8];
#pragma unroll
        for (int nt = 0; nt < 3; ++nt) {
            bf16x8 b = *(const bf16x8*)&Bs[nt * 16 + lm][ks * 32 + lk * 8];
            acc[nt] = __builtin_amdgcn_mfma_f32_16x16x32_bf16(a, b, acc[nt], 0, 0, 0);
        }
    }
#pragma unroll
    for (int nt = 0; nt < 3; ++nt) {
        int col = nt * 16 + lm;
        if (col < OUT_DIM) {
            float bbv = hb[col];
#pragma unroll
            for (int j = 0; j < 4; ++j) {
                int r = brow + w * 16 + lk * 4 + j;
                if (r < N) out[(size_t)r * OUT_DIM + col] = acc[nt][j] + bbv;
            }
        }
    }
}

// ---------------- launch ----------------

extern "C" void kernel_launch(void* const* d_in, const int* in_sizes, int n_in,
                              void* d_out, int out_size, void* d_ws, size_t ws_size,
                              hipStream_t stream) {
    const float* x   = (const float*)d_in[0];
    const int*   ei  = (const int*)d_in[1];
    const float* W0  = (const float*)d_in[2];
    // d_in[3] = b0: cancels in BatchNorm
    const float* g0  = (const float*)d_in[4];
    const float* be0 = (const float*)d_in[5];
    const float* pW  = (const float*)d_in[6];
    const float* pb  = (const float*)d_in[7];
    const float* W1  = (const float*)d_in[8];
    // d_in[9] = b1: cancels in BatchNorm
    const float* g1  = (const float*)d_in[10];
    const float* be1 = (const float*)d_in[11];
    const float* hW  = (const float*)d_in[12];
    const float* hb  = (const float*)d_in[13];
    float* out = (float*)d_out;

    int N = in_sizes[0] / IN_DIM;
    int E = in_sizes[1] / 2;
    size_t NH = (size_t)N * H;

    // workspace layout (all bf16 intermediates)
    ushortT* hb16   = (ushortT*)d_ws;            // [N,128] conv input h
    ushortT* aggb   = hb16 + NH;                 // [N,128] aggregated
    ushortT* projb  = aggb + NH;                 // [N,128] proj (block0)
    ushortT* x1b    = projb + NH;                // [N,128] x1
    float*   dis    = (float*)(x1b + NH);        // [N]
    int*     cnt    = (int*)(dis + N);           // [N]
    int*     rowptr = cnt + N;                   // [N+1]
    int*     cursor = rowptr + (N + 1);          // [N]
    int*     eidx   = cursor + N;                // [E]
    float*   stats  = (float*)(eidx + E);        // [256]
    ushortT* Wt0    = (ushortT*)(stats + 256);   // [128*256]
    ushortT* WtP    = Wt0 + 128 * 256;           // [128*256]
    ushortT* Wt1    = WtP + 128 * 256;           // [128*128]
    ushortT* WtH    = Wt1 + 128 * 128;           // [48*128]
    int*     bsum   = (int*)(WtH + 48 * 128);    // [256]
    int*     boff   = bsum + 256;                // [256]

    int gE = (E + 255) / 256;
    int nb = (N + 255) / 256;
    int g64 = (N + 63) / 64;
    int g128 = (N + 127) / 128;
    int gAgg = (N + 3) / 4;

    // CSR build + weight prep
    hipMemsetAsync(cnt, 0, (size_t)N * sizeof(int), stream);
    prep_weights<<<128, 256, 0, stream>>>(W0, pW, W1, hW, Wt0, WtP, Wt1, WtH);
    count_kernel<<<gE, 256, 0, stream>>>(ei, E, cnt);
    scan_block_sum<<<nb, 256, 0, stream>>>(cnt, bsum, dis, N);
    scan_tops<<<1, 256, 0, stream>>>(bsum, boff, &rowptr[N], nb);
    scan_final<<<nb, 256, 0, stream>>>(cnt, boff, rowptr, cursor, N);
    fill_xcd<<<2048, 256, 0, stream>>>(ei, E, (N + 7) / 8, cursor, eidx);

    // block 0
    mgemm0<<<g64, 512, 0, stream>>>(x, Wt0, WtP, pb, hb16, projb, N);
    aggregate_bf<<<gAgg, 256, 0, stream>>>(hb16, rowptr, eidx, dis, aggb, N);
    hipMemsetAsync(stats, 0, 256 * sizeof(float), stream);
    stats_bf<<<256, 256, 0, stream>>>((const unsigned*)aggb, (int)(NH / 2), stats);

    // block 1 (x1 = relu(bn0(agg)) + proj fused into GEMM1's staging; x1 also written for head)
    mgemm1_fused<<<g128, 512, 0, stream>>>((const uint4*)aggb, (const uint4*)projb, stats, g0, be0,
                                           Wt1, hb16, (uint4*)x1b, N);
    aggregate_bf<<<gAgg, 256, 0, stream>>>(hb16, rowptr, eidx, dis, aggb, N);
    hipMemsetAsync(stats, 0, 256 * sizeof(float), stream);
    stats_bf<<<256, 256, 0, stream>>>((const unsigned*)aggb, (int)(NH / 2), stats);

    // head (x2 computed inline)
    head_fused<<<g64, 256, 0, stream>>>((const uint4*)aggb, (const uint4*)x1b, stats, g1, be1,
                                        WtH, hb, out, N);
}

// Round 7
// 261.595 us; speedup vs baseline: 2.3953x; 1.0029x over previous
//
#include <hip/hip_runtime.h>

#define H 128
#define IN_DIM 256
#define OUT_DIM 40
#define EPS 1e-5f

typedef unsigned short ushortT;
typedef __attribute__((ext_vector_type(8))) short bf16x8;
typedef __attribute__((ext_vector_type(4))) float f32x4;

static __device__ __forceinline__ ushortT f2bf(float f) {
    union { float f; unsigned u; } v; v.f = f;
    unsigned r = v.u + 0x7FFF + ((v.u >> 16) & 1);   // RNE
    return (ushortT)(r >> 16);
}
static __device__ __forceinline__ unsigned pk2(float a, float b) {
    return (unsigned)f2bf(a) | ((unsigned)f2bf(b) << 16);
}
static __device__ __forceinline__ float bflo(unsigned v) {
    union { unsigned u; float f; } t; t.u = v << 16; return t.f;
}
static __device__ __forceinline__ float bfhi(unsigned v) {
    union { unsigned u; float f; } t; t.u = v & 0xFFFF0000u; return t.f;
}
static __device__ __forceinline__ float i2f(int v) {
    union { int i; float f; } t; t.i = v; return t.f;
}
static __device__ __forceinline__ int f2i(float v) {
    union { float f; int i; } t; t.f = v; return t.i;
}

// ---------------- CSR build ----------------

// XCD-partitioned count: atomics on cnt stay within one node-window (one L2).
__global__ __launch_bounds__(256) void count_xcd(const int* __restrict__ ei, int E, int nper,
                                                 int* __restrict__ cnt) {
    int xcd = blockIdx.x & 7;
    int nchunk = gridDim.x >> 3;
    int chunk = blockIdx.x >> 3;
    int csz = (E + nchunk - 1) / nchunk;
    int beg = chunk * csz;
    int end = min(E, beg + csz);
    for (int e = beg + (int)threadIdx.x; e < end; e += 256) {
        int c = ei[E + e];
        if (c / nper == xcd) atomicAdd(&cnt[c], 1);
    }
}

// block sums of (cnt+1) (self record included); also dis = rsqrt(cnt+2)
__global__ __launch_bounds__(256) void scan_block_sum(const int* __restrict__ cnt, int* __restrict__ bsum,
                                                      float* __restrict__ dis, int N) {
    __shared__ int s[256];
    int i = blockIdx.x * 256 + threadIdx.x;
    int c = (i < N) ? cnt[i] : -1;
    int v = (i < N) ? c + 1 : 0;
    if (i < N) dis[i] = rsqrtf((float)c + 2.0f);
    s[threadIdx.x] = v;
    __syncthreads();
    for (int o = 128; o > 0; o >>= 1) {
        if (threadIdx.x < o) s[threadIdx.x] += s[threadIdx.x + o];
        __syncthreads();
    }
    if (threadIdx.x == 0) bsum[blockIdx.x] = s[0];
}

__global__ void scan_tops(const int* __restrict__ bsum, int* __restrict__ boff, int* __restrict__ rowptrN, int nb) {
    __shared__ int s[256];
    int t = threadIdx.x;
    int v = (t < nb) ? bsum[t] : 0;
    s[t] = v;
    __syncthreads();
    for (int o = 1; o < 256; o <<= 1) {
        int u = (t >= o) ? s[t - o] : 0;
        __syncthreads();
        s[t] += u;
        __syncthreads();
    }
    if (t < nb) boff[t] = s[t] - v;
    if (t == 255) *rowptrN = s[255];
}

// rowptr/cursor; writes the self-loop record {n, 2*dis^2} at slot rowptr[n]
__global__ __launch_bounds__(256) void scan_final(const int* __restrict__ cnt, const int* __restrict__ boff,
                                                  const float* __restrict__ dis,
                                                  int* __restrict__ rowptr, int* __restrict__ cursor,
                                                  int2* __restrict__ recs, int N) {
    __shared__ int s[256];
    int t = threadIdx.x;
    int i = blockIdx.x * 256 + t;
    int v = (i < N) ? cnt[i] + 1 : 0;
    s[t] = v;
    __syncthreads();
    for (int o = 1; o < 256; o <<= 1) {
        int u = (t >= o) ? s[t - o] : 0;
        __syncthreads();
        s[t] += u;
        __syncthreads();
    }
    if (i < N) {
        int e = boff[blockIdx.x] + s[t] - v;
        rowptr[i] = e;
        cursor[i] = e + 1;                    // slot e holds the self record
        float d = dis[i];
        int2 r; r.x = i; r.y = f2i(2.0f * d * d);
        recs[e] = r;
    }
}

// XCD-partitioned fill; writes (src, dis[src]*dis[dst]) records
__global__ __launch_bounds__(256) void fill_xcd(const int* __restrict__ ei, int E, int nper,
                                                const float* __restrict__ dis,
                                                int* __restrict__ cursor, int2* __restrict__ recs) {
    int xcd = blockIdx.x & 7;
    int nchunk = gridDim.x >> 3;
    int chunk = blockIdx.x >> 3;
    int csz = (E + nchunk - 1) / nchunk;
    int beg = chunk * csz;
    int end = min(E, beg + csz);
    for (int e = beg + (int)threadIdx.x; e < end; e += 256) {
        int c = ei[E + e];
        if (c / nper == xcd) {
            int r = ei[e];
            int slot = atomicAdd(&cursor[c], 1);
            int2 rec; rec.x = r; rec.y = f2i(dis[r] * dis[c]);
            recs[slot] = rec;
        }
    }
}

// ---------------- weight prep: transpose + bf16 (also zeroes cnt + stats) ----------------

__global__ __launch_bounds__(256) void prep_weights(const float* __restrict__ W0, const float* __restrict__ pW,
                                                    const float* __restrict__ W1, const float* __restrict__ hW,
                                                    ushortT* __restrict__ Wt0, ushortT* __restrict__ WtP,
                                                    ushortT* __restrict__ Wt1, ushortT* __restrict__ WtH,
                                                    int* __restrict__ cnt, float* __restrict__ stats, int N) {
    int i = blockIdx.x * 256 + threadIdx.x;
    if (i < 32768) { int n = i >> 8, k = i & 255; Wt0[i] = f2bf(W0[k * 128 + n]); WtP[i] = f2bf(pW[k * 128 + n]); }
    if (i < 16384) { int n = i >> 7, k = i & 127; Wt1[i] = f2bf(W1[k * 128 + n]); }
    if (i < 6144)  { int n = i >> 7, k = i & 127; WtH[i] = (n < OUT_DIM) ? f2bf(hW[k * OUT_DIM + n]) : (ushortT)0; }
    if (i < N) cnt[i] = 0;
    if (i < 512) stats[i] = 0.f;
}

// ---------------- GEMM0 persistent: dual (h = x@W0, proj = x@pW + pb) ----------------
// 512 threads (8 waves), BM=64, B entirely in regs (per-wave 64 VGPRs), K split in 2 chunks of 128,
// LDS double-buffered per chunk with issue-early loads. Each block handles tiles {bid, bid+G, ...}.

static __device__ __forceinline__ void g0_loads(const float* __restrict__ X, int brow, int kc,
                                                int tid, int N, float4 pf[4]) {
#pragma unroll
    for (int i = 0; i < 4; ++i) {
        int idx = i * 512 + tid;
        int row = idx >> 5, c4 = idx & 31;
        int gr = brow + row;
        pf[i] = make_float4(0.f, 0.f, 0.f, 0.f);
        if (gr < N) pf[i] = *(const float4*)&X[(size_t)gr * IN_DIM + kc * 128 + c4 * 4];
    }
}
static __device__ __forceinline__ void g0_write(ushortT* __restrict__ Sbuf, int tid, const float4 pf[4]) {
#pragma unroll
    for (int i = 0; i < 4; ++i) {
        int idx = i * 512 + tid;
        int row = idx >> 5, c4 = idx & 31;
        uint2 p;
        p.x = pk2(pf[i].x, pf[i].y);
        p.y = pk2(pf[i].z, pf[i].w);
        *(uint2*)&Sbuf[row * 136 + c4 * 4] = p;
    }
}

__global__ __launch_bounds__(512) void mgemm0p(const float* __restrict__ X,
                                               const ushortT* __restrict__ Wt0,
                                               const ushortT* __restrict__ WtP,
                                               const float* __restrict__ pb,
                                               ushortT* __restrict__ Oh,
                                               ushortT* __restrict__ Op,
                                               int N, int ntiles) {
    __shared__ __align__(16) ushortT S[2][64 * 136];
    int tid = threadIdx.x;
    int w = tid >> 6, lane = tid & 63;
    int lm = lane & 15, lk = lane >> 4;
    int mat = w >> 2;
    int colbase = (w & 3) * 32;
    const ushortT* Wt = mat ? WtP : Wt0;

    bf16x8 breg[2][8];
#pragma unroll
    for (int nt = 0; nt < 2; ++nt)
#pragma unroll
        for (int kk = 0; kk < 8; ++kk)
            breg[nt][kk] = *(const bf16x8*)&Wt[(size_t)(colbase + nt * 16 + lm) * IN_DIM + kk * 32 + lk * 8];
    float bb[2];
    bb[0] = mat ? pb[colbase + lm] : 0.f;
    bb[1] = mat ? pb[colbase + 16 + lm] : 0.f;
    ushortT* O = mat ? Op : Oh;

    int bid = blockIdx.x, G = gridDim.x;
    int T = (ntiles - 1 - bid) / G + 1;        // >=1 since G <= ntiles
    int U = 2 * T;

    float4 pf[4];
    g0_loads(X, bid * 64, 0, tid, N, pf);
    g0_write(S[0], tid, pf);

    f32x4 acc[4][2];
#pragma unroll
    for (int mt = 0; mt < 4; ++mt)
#pragma unroll
        for (int nt = 0; nt < 2; ++nt) acc[mt][nt] = (f32x4)0.f;

    for (int u = 0; u < U; ++u) {
        __syncthreads();                        // S[u&1] staged
        if (u + 1 < U) {
            int t1 = bid + ((u + 1) >> 1) * G;
            g0_loads(X, t1 * 64, (u + 1) & 1, tid, N, pf);   // issue early, hide under MFMA
        }
        int kc = u & 1;
        const ushortT* Sc = S[u & 1];
#pragma unroll
        for (int kk = 0; kk < 4; ++kk) {
            bf16x8 af[4];
#pragma unroll
            for (int mt = 0; mt < 4; ++mt)
                af[mt] = *(const bf16x8*)&Sc[(mt * 16 + lm) * 136 + kk * 32 + lk * 8];
#pragma unroll
            for (int nt = 0; nt < 2; ++nt)
#pragma unroll
                for (int mt = 0; mt < 4; ++mt)
                    acc[mt][nt] = __builtin_amdgcn_mfma_f32_16x16x32_bf16(af[mt], breg[nt][kc * 4 + kk], acc[mt][nt], 0, 0, 0);
        }
        if (u + 1 < U) g0_write(S[(u + 1) & 1], tid, pf);   // other buffer: safe without barrier
        if (kc == 1) {
            int t = bid + (u >> 1) * G;
            int brow = t * 64;
#pragma unroll
            for (int mt = 0; mt < 4; ++mt)
#pragma unroll
                for (int nt = 0; nt < 2; ++nt) {
                    int col = colbase + nt * 16 + lm;
#pragma unroll
                    for (int j = 0; j < 4; ++j) {
                        int r = brow + mt * 16 + lk * 4 + j;
                        if (r < N) O[(size_t)r * 128 + col] = f2bf(acc[mt][nt][j] + bb[nt]);
                    }
                    acc[mt][nt] = (f32x4)0.f;
                }
        }
    }
}

// ---------------- GEMM1 fused: x1 = relu(bn0(agg)) + proj (written out), h = x1 @ W1, LDS epilogue ----------------

__global__ __launch_bounds__(512) void mgemm1_fused(const uint4* __restrict__ aggb,
                                                    const uint4* __restrict__ projb,
                                                    const float* __restrict__ stats,
                                                    const float* __restrict__ g,
                                                    const float* __restrict__ be,
                                                    const ushortT* __restrict__ Wt1,
                                                    ushortT* __restrict__ O,
                                                    uint4* __restrict__ x1b,
                                                    int N) {
    __shared__ __align__(16) ushortT S[17408];
    __shared__ float sc[128], sh[128];
    int tid = threadIdx.x;
    int brow = blockIdx.x * 128;

    if (tid < 128) {
        float mean = stats[tid] / (float)N;
        float var = stats[128 + tid] / (float)N - mean * mean;
        float inv = rsqrtf(var + EPS);
        float s = g[tid] * inv;
        sc[tid] = s;
        sh[tid] = be[tid] - mean * s;
    }
    __syncthreads();

#pragma unroll
    for (int i = 0; i < 4; ++i) {
        int idx = i * 512 + tid;
        int row = idx >> 4, q = idx & 15;
        int gr = brow + row;
        uint4 a = make_uint4(0u, 0u, 0u, 0u), p = a;
        if (gr < N) {
            size_t gidx = (size_t)gr * 16 + q;
            a = aggb[gidx];
            p = projb[gidx];
        }
        int ch = q * 8;
        float v0 = fmaxf(fmaf(bflo(a.x), sc[ch + 0], sh[ch + 0]), 0.f) + bflo(p.x);
        float v1 = fmaxf(fmaf(bfhi(a.x), sc[ch + 1], sh[ch + 1]), 0.f) + bfhi(p.x);
        float v2 = fmaxf(fmaf(bflo(a.y), sc[ch + 2], sh[ch + 2]), 0.f) + bflo(p.y);
        float v3 = fmaxf(fmaf(bfhi(a.y), sc[ch + 3], sh[ch + 3]), 0.f) + bfhi(p.y);
        float v4 = fmaxf(fmaf(bflo(a.z), sc[ch + 4], sh[ch + 4]), 0.f) + bflo(p.z);
        float v5 = fmaxf(fmaf(bfhi(a.z), sc[ch + 5], sh[ch + 5]), 0.f) + bfhi(p.z);
        float v6 = fmaxf(fmaf(bflo(a.w), sc[ch + 6], sh[ch + 6]), 0.f) + bflo(p.w);
        float v7 = fmaxf(fmaf(bfhi(a.w), sc[ch + 7], sh[ch + 7]), 0.f) + bfhi(p.w);
        uint4 pv;
        pv.x = pk2(v0, v1);
        pv.y = pk2(v2, v3);
        pv.z = pk2(v4, v5);
        pv.w = pk2(v6, v7);
        *(uint4*)&S[row * 136 + q * 8] = pv;
        if (gr < N) x1b[(size_t)gr * 16 + q] = pv;
    }
    __syncthreads();

    int w = tid >> 6, lane = tid & 63;
    int lm = lane & 15, lk = lane >> 4;
    int rh = (w >> 2) * 64;
    int colbase = (w & 3) * 32;

    bf16x8 breg[2][4];
#pragma unroll
    for (int nt = 0; nt < 2; ++nt)
#pragma unroll
        for (int ks = 0; ks < 4; ++ks)
            breg[nt][ks] = *(const bf16x8*)&Wt1[(size_t)(colbase + nt * 16 + lm) * H + ks * 32 + lk * 8];

    f32x4 acc[4][2];
#pragma unroll
    for (int mt = 0; mt < 4; ++mt)
#pragma unroll
        for (int nt = 0; nt < 2; ++nt) acc[mt][nt] = (f32x4)0.f;

#pragma unroll
    for (int ks = 0; ks < 4; ++ks) {
        bf16x8 af[4];
#pragma unroll
        for (int mt = 0; mt < 4; ++mt)
            af[mt] = *(const bf16x8*)&S[(rh + mt * 16 + lm) * 136 + ks * 32 + lk * 8];
#pragma unroll
        for (int nt = 0; nt < 2; ++nt)
#pragma unroll
            for (int mt = 0; mt < 4; ++mt)
                acc[mt][nt] = __builtin_amdgcn_mfma_f32_16x16x32_bf16(af[mt], breg[nt][ks], acc[mt][nt], 0, 0, 0);
    }

    __syncthreads();
#pragma unroll
    for (int mt = 0; mt < 4; ++mt)
#pragma unroll
        for (int nt = 0; nt < 2; ++nt) {
            int col = colbase + nt * 16 + lm;
#pragma unroll
            for (int j = 0; j < 4; ++j) {
                int row = rh + mt * 16 + lk * 4 + j;
                S[row * 136 + col] = f2bf(acc[mt][nt][j]);
            }
        }
    __syncthreads();
#pragma unroll
    for (int i = 0; i < 4; ++i) {
        int idx = i * 512 + tid;
        int row = idx >> 4, colq = idx & 15;
        int gr = brow + row;
        if (gr < N) {
            uint4 v = *(const uint4*)&S[row * 136 + colq * 8];
            *(uint4*)&O[(size_t)gr * 128 + colq * 8] = v;
        }
    }
}

// ---------------- aggregation: wave per node, half-wave edge split, premult records ----------------
// lanes 0-31 handle even record slots, 32-63 odd. lane cl owns channels 4cl..4cl+3 (uint2 = 4 bf16).

__global__ __launch_bounds__(256) void aggregate_rec(const ushortT* __restrict__ h,
                                                     const int* __restrict__ rowptr,
                                                     const int2* __restrict__ recs,
                                                     ushortT* __restrict__ aggb, int N) {
    int n = blockIdx.x * 4 + (threadIdx.x >> 6);
    if (n >= N) return;
    int lane = threadIdx.x & 63;
    int half = lane >> 5, cl = lane & 31;
    int beg = rowptr[n], end = rowptr[n + 1];
    const uint2* h2 = (const uint2*)h;           // 8B units; row stride 32
    float a0 = 0.f, a1 = 0.f, a2 = 0.f, a3 = 0.f;
    float b0 = 0.f, b1 = 0.f, b2 = 0.f, b3 = 0.f;
    int idx = beg + half;
    for (; idx + 2 < end; idx += 4) {
        int2 r0 = recs[idx];
        int2 r1 = recs[idx + 2];
        uint2 v0 = h2[(size_t)r0.x * 32 + cl];
        uint2 v1 = h2[(size_t)r1.x * 32 + cl];
        float n0 = i2f(r0.y), n1 = i2f(r1.y);
        a0 = fmaf(n0, bflo(v0.x), a0); a1 = fmaf(n0, bfhi(v0.x), a1);
        a2 = fmaf(n0, bflo(v0.y), a2); a3 = fmaf(n0, bfhi(v0.y), a3);
        b0 = fmaf(n1, bflo(v1.x), b0); b1 = fmaf(n1, bfhi(v1.x), b1);
        b2 = fmaf(n1, bflo(v1.y), b2); b3 = fmaf(n1, bfhi(v1.y), b3);
    }
    if (idx < end) {
        int2 r0 = recs[idx];
        uint2 v0 = h2[(size_t)r0.x * 32 + cl];
        float n0 = i2f(r0.y);
        a0 = fmaf(n0, bflo(v0.x), a0); a1 = fmaf(n0, bfhi(v0.x), a1);
        a2 = fmaf(n0, bflo(v0.y), a2); a3 = fmaf(n0, bfhi(v0.y), a3);
    }
    a0 += b0; a1 += b1; a2 += b2; a3 += b3;
    a0 += __shfl_xor(a0, 32);
    a1 += __shfl_xor(a1, 32);
    a2 += __shfl_xor(a2, 32);
    a3 += __shfl_xor(a3, 32);
    if (half == 0) {
        uint2 o;
        o.x = pk2(a0, a1);
        o.y = pk2(a2, a3);
        ((uint2*)aggb)[(size_t)n * 32 + cl] = o;
    }
}

// ---------------- BN stats from bf16 (raw sums) ----------------

__global__ __launch_bounds__(256) void stats_bf(const unsigned* __restrict__ v, int totalU,
                                                float* __restrict__ sums) {
    int tid = blockIdx.x * 256 + threadIdx.x;
    int stride = gridDim.x * 256;
    float sx = 0.f, sy = 0.f, qx = 0.f, qy = 0.f;
    for (int i = tid; i < totalU; i += stride) {
        unsigned u = v[i];
        float a = bflo(u), b = bfhi(u);
        sx += a; sy += b;
        qx = fmaf(a, a, qx); qy = fmaf(b, b, qy);
    }
    __shared__ float l0[256], l1[256], l2[256], l3[256];
    int t = threadIdx.x;
    l0[t] = sx; l1[t] = sy; l2[t] = qx; l3[t] = qy;
    __syncthreads();
    if (t < 64) {
        sx = (l0[t] + l0[t + 64]) + (l0[t + 128] + l0[t + 192]);
        sy = (l1[t] + l1[t + 64]) + (l1[t + 128] + l1[t + 192]);
        qx = (l2[t] + l2[t + 64]) + (l2[t + 128] + l2[t + 192]);
        qy = (l3[t] + l3[t + 64]) + (l3[t + 128] + l3[t + 192]);
        atomicAdd(&sums[2 * t], sx);
        atomicAdd(&sums[2 * t + 1], sy);
        atomicAdd(&sums[128 + 2 * t], qx);
        atomicAdd(&sums[128 + 2 * t + 1], qy);
    }
}

// ---------------- head: out = (relu(bn1(agg)) + x1) @ hW + hb, x2 inline ----------------

__global__ __launch_bounds__(256) void head_fused(const uint4* __restrict__ aggb,
                                                  const uint4* __restrict__ x1b,
                                                  const float* __restrict__ stats,
                                                  const float* __restrict__ g,
                                                  const float* __restrict__ be,
                                                  const ushortT* __restrict__ WtH,
                                                  const float* __restrict__ hb,
                                                  float* __restrict__ out, int N) {
    __shared__ __align__(16) ushortT As[64][136];
    __shared__ __align__(16) ushortT Bs[48][136];
    __shared__ float sc[128], sh[128];

    int tid = threadIdx.x;
    int brow = blockIdx.x * 64;
    int w = tid >> 6, lane = tid & 63;
    int lm = lane & 15, lk = lane >> 4;

    if (tid < 128) {
        float mean = stats[tid] / (float)N;
        float var = stats[128 + tid] / (float)N - mean * mean;
        float inv = rsqrtf(var + EPS);
        float s = g[tid] * inv;
        sc[tid] = s;
        sh[tid] = be[tid] - mean * s;
    }
    if (tid < 192) {
        int row = tid >> 2, q = tid & 3;
        const uint4* src = (const uint4*)&WtH[(size_t)row * H + q * 32];
        uint4 a = src[0], b = src[1], c = src[2], d = src[3];
        uint4* dst = (uint4*)&Bs[row][q * 32];
        dst[0] = a; dst[1] = b; dst[2] = c; dst[3] = d;
    }
    __syncthreads();
#pragma unroll
    for (int k = 0; k < 4; ++k) {
        int idx = k * 256 + tid;
        int row = idx >> 4, colq = idx & 15;
        int gr = brow + row;
        uint4 a = make_uint4(0u, 0u, 0u, 0u), x = a;
        if (gr < N) {
            size_t gidx = (size_t)brow * 16 + idx;
            a = aggb[gidx];
            x = x1b[gidx];
        }
        int ch = colq * 8;
        float v0 = fmaxf(fmaf(bflo(a.x), sc[ch + 0], sh[ch + 0]), 0.f) + bflo(x.x);
        float v1 = fmaxf(fmaf(bfhi(a.x), sc[ch + 1], sh[ch + 1]), 0.f) + bfhi(x.x);
        float v2 = fmaxf(fmaf(bflo(a.y), sc[ch + 2], sh[ch + 2]), 0.f) + bflo(x.y);
        float v3 = fmaxf(fmaf(bfhi(a.y), sc[ch + 3], sh[ch + 3]), 0.f) + bfhi(x.y);
        float v4 = fmaxf(fmaf(bflo(a.z), sc[ch + 4], sh[ch + 4]), 0.f) + bflo(x.z);
        float v5 = fmaxf(fmaf(bfhi(a.z), sc[ch + 5], sh[ch + 5]), 0.f) + bfhi(x.z);
        float v6 = fmaxf(fmaf(bflo(a.w), sc[ch + 6], sh[ch + 6]), 0.f) + bflo(x.w);
        float v7 = fmaxf(fmaf(bfhi(a.w), sc[ch + 7], sh[ch + 7]), 0.f) + bfhi(x.w);
        uint4 pv;
        pv.x = pk2(v0, v1);
        pv.y = pk2(v2, v3);
        pv.z = pk2(v4, v5);
        pv.w = pk2(v6, v7);
        *(uint4*)&As[row][colq * 8] = pv;
    }
    __syncthreads();

    f32x4 acc[3];
#pragma unroll
    for (int nt = 0; nt < 3; ++nt) acc[nt] = (f32x4)0.f;
#pragma unroll
    for (int ks = 0; ks < 4; ++ks) {
        bf16x8 a = *(const bf16x8*)&As[w * 16 + lm][ks * 32 + lk * 8];
#pragma unroll
        for (int nt = 0; nt < 3; ++nt) {
            bf16x8 b = *(const bf16x8*)&Bs[nt * 16 + lm][ks * 32 + lk * 8];
            acc[nt] = __builtin_amdgcn_mfma_f32_16x16x32_bf16(a, b, acc[nt], 0, 0, 0);
        }
    }
#pragma unroll
    for (int nt = 0; nt < 3; ++nt) {
        int col = nt * 16 + lm;
        if (col < OUT_DIM) {
            float bbv = hb[col];
#pragma unroll
            for (int j = 0; j < 4; ++j) {
                int r = brow + w * 16 + lk * 4 + j;
                if (r < N) out[(size_t)r * OUT_DIM + col] = acc[nt][j] + bbv;
            }
        }
    }
}

// ---------------- launch ----------------

extern "C" void kernel_launch(void* const* d_in, const int* in_sizes, int n_in,
                              void* d_out, int out_size, void* d_ws, size_t ws_size,
                              hipStream_t stream) {
    const float* x   = (const float*)d_in[0];
    const int*   ei  = (const int*)d_in[1];
    const float* W0  = (const float*)d_in[2];
    // d_in[3] = b0: cancels in BatchNorm
    const float* g0  = (const float*)d_in[4];
    const float* be0 = (const float*)d_in[5];
    const float* pW  = (const float*)d_in[6];
    const float* pb  = (const float*)d_in[7];
    const float* W1  = (const float*)d_in[8];
    // d_in[9] = b1: cancels in BatchNorm
    const float* g1  = (const float*)d_in[10];
    const float* be1 = (const float*)d_in[11];
    const float* hW  = (const float*)d_in[12];
    const float* hb  = (const float*)d_in[13];
    float* out = (float*)d_out;

    int N = in_sizes[0] / IN_DIM;
    int E = in_sizes[1] / 2;
    size_t NH = (size_t)N * H;

    // workspace layout (all bf16 intermediates)
    ushortT* hb16   = (ushortT*)d_ws;            // [N,128] conv input h
    ushortT* aggb   = hb16 + NH;                 // [N,128] aggregated
    ushortT* projb  = aggb + NH;                 // [N,128] proj (block0)
    ushortT* x1b    = projb + NH;                // [N,128] x1
    float*   dis    = (float*)(x1b + NH);        // [N]
    int*     cnt    = (int*)(dis + N);           // [N]
    int*     rowptr = cnt + N;                   // [N+1]
    int*     cursor = rowptr + (N + 1);          // [N]
    int2*    recs   = (int2*)(cursor + N);       // [E+N] (8B-aligned)
    float*   stats  = (float*)(recs + (E + N));  // [512]: block0 then block1
    ushortT* Wt0    = (ushortT*)(stats + 512);   // [128*256]
    ushortT* WtP    = Wt0 + 128 * 256;           // [128*256]
    ushortT* Wt1    = WtP + 128 * 256;           // [128*128]
    ushortT* WtH    = Wt1 + 128 * 128;           // [48*128]
    int*     bsum   = (int*)(WtH + 48 * 128);    // [256]
    int*     boff   = bsum + 256;                // [256]
    float*   stats0 = stats;
    float*   stats1 = stats + 256;

    int nb = (N + 255) / 256;
    int g64 = (N + 63) / 64;
    int g128 = (N + 127) / 128;
    int gAgg = (N + 3) / 4;
    int ntiles = g64;
    int gPersist = (ntiles + 1) / 2;             // 2 tiles per block

    // prep (weights + zero cnt/stats), CSR build
    prep_weights<<<196, 256, 0, stream>>>(W0, pW, W1, hW, Wt0, WtP, Wt1, WtH, cnt, stats, N);
    count_xcd<<<2048, 256, 0, stream>>>(ei, E, (N + 7) / 8, cnt);
    scan_block_sum<<<nb, 256, 0, stream>>>(cnt, bsum, dis, N);
    scan_tops<<<1, 256, 0, stream>>>(bsum, boff, &rowptr[N], nb);
    scan_final<<<nb, 256, 0, stream>>>(cnt, boff, dis, rowptr, cursor, recs, N);
    fill_xcd<<<2048, 256, 0, stream>>>(ei, E, (N + 7) / 8, dis, cursor, recs);

    // block 0
    mgemm0p<<<gPersist, 512, 0, stream>>>(x, Wt0, WtP, pb, hb16, projb, N, ntiles);
    aggregate_rec<<<gAgg, 256, 0, stream>>>(hb16, rowptr, recs, aggb, N);
    stats_bf<<<256, 256, 0, stream>>>((const unsigned*)aggb, (int)(NH / 2), stats0);

    // block 1 (x1 = relu(bn0(agg)) + proj fused into GEMM1's staging; x1 also written for head)
    mgemm1_fused<<<g128, 512, 0, stream>>>((const uint4*)aggb, (const uint4*)projb, stats0, g0, be0,
                                           Wt1, hb16, (uint4*)x1b, N);
    aggregate_rec<<<gAgg, 256, 0, stream>>>(hb16, rowptr, recs, aggb, N);
    stats_bf<<<256, 256, 0, stream>>>((const unsigned*)aggb, (int)(NH / 2), stats1);

    // head (x2 computed inline)
    head_fused<<<g64, 256, 0, stream>>>((const uint4*)aggb, (const uint4*)x1b, stats1, g1, be1,
                                        WtH, hb, out, N);
}

// Round 8
// 251.743 us; speedup vs baseline: 2.4890x; 1.0391x over previous
//
#include <hip/hip_runtime.h>

#define H 128
#define IN_DIM 256
#define OUT_DIM 40
#define EPS 1e-5f

typedef unsigned short ushortT;
typedef __attribute__((ext_vector_type(8))) short bf16x8;
typedef __attribute__((ext_vector_type(4))) float f32x4;

static __device__ __forceinline__ ushortT f2bf(float f) {
    union { float f; unsigned u; } v; v.f = f;
    unsigned r = v.u + 0x7FFF + ((v.u >> 16) & 1);   // RNE
    return (ushortT)(r >> 16);
}
static __device__ __forceinline__ unsigned pk2(float a, float b) {
    return (unsigned)f2bf(a) | ((unsigned)f2bf(b) << 16);
}
static __device__ __forceinline__ float bflo(unsigned v) {
    union { unsigned u; float f; } t; t.u = v << 16; return t.f;
}
static __device__ __forceinline__ float bfhi(unsigned v) {
    union { unsigned u; float f; } t; t.u = v & 0xFFFF0000u; return t.f;
}
static __device__ __forceinline__ float i2f(int v) {
    union { int i; float f; } t; t.i = v; return t.f;
}
static __device__ __forceinline__ int f2i(float v) {
    union { float f; int i; } t; t.f = v; return t.i;
}

// ---------------- CSR build ----------------

// XCD-partitioned count: atomics on cnt stay within one node-window (one L2).
__global__ __launch_bounds__(256) void count_xcd(const int* __restrict__ ei, int E, int nper,
                                                 int* __restrict__ cnt) {
    int xcd = blockIdx.x & 7;
    int nchunk = gridDim.x >> 3;
    int chunk = blockIdx.x >> 3;
    int csz = (E + nchunk - 1) / nchunk;
    int beg = chunk * csz;
    int end = min(E, beg + csz);
    for (int e = beg + (int)threadIdx.x; e < end; e += 256) {
        int c = ei[E + e];
        if (c / nper == xcd) atomicAdd(&cnt[c], 1);
    }
}

// block sums of (cnt+1) (self record included); also dis = rsqrt(cnt+2)
__global__ __launch_bounds__(256) void scan_block_sum(const int* __restrict__ cnt, int* __restrict__ bsum,
                                                      float* __restrict__ dis, int N) {
    __shared__ int s[256];
    int i = blockIdx.x * 256 + threadIdx.x;
    int c = (i < N) ? cnt[i] : -1;
    int v = (i < N) ? c + 1 : 0;
    if (i < N) dis[i] = rsqrtf((float)c + 2.0f);
    s[threadIdx.x] = v;
    __syncthreads();
    for (int o = 128; o > 0; o >>= 1) {
        if (threadIdx.x < o) s[threadIdx.x] += s[threadIdx.x + o];
        __syncthreads();
    }
    if (threadIdx.x == 0) bsum[blockIdx.x] = s[0];
}

__global__ void scan_tops(const int* __restrict__ bsum, int* __restrict__ boff, int* __restrict__ rowptrN, int nb) {
    __shared__ int s[256];
    int t = threadIdx.x;
    int v = (t < nb) ? bsum[t] : 0;
    s[t] = v;
    __syncthreads();
    for (int o = 1; o < 256; o <<= 1) {
        int u = (t >= o) ? s[t - o] : 0;
        __syncthreads();
        s[t] += u;
        __syncthreads();
    }
    if (t < nb) boff[t] = s[t] - v;
    if (t == 255) *rowptrN = s[255];
}

// rowptr/cursor; writes the self-loop record {n, 2*dis^2} at slot rowptr[n]
__global__ __launch_bounds__(256) void scan_final(const int* __restrict__ cnt, const int* __restrict__ boff,
                                                  const float* __restrict__ dis,
                                                  int* __restrict__ rowptr, int* __restrict__ cursor,
                                                  int2* __restrict__ recs, int N) {
    __shared__ int s[256];
    int t = threadIdx.x;
    int i = blockIdx.x * 256 + t;
    int v = (i < N) ? cnt[i] + 1 : 0;
    s[t] = v;
    __syncthreads();
    for (int o = 1; o < 256; o <<= 1) {
        int u = (t >= o) ? s[t - o] : 0;
        __syncthreads();
        s[t] += u;
        __syncthreads();
    }
    if (i < N) {
        int e = boff[blockIdx.x] + s[t] - v;
        rowptr[i] = e;
        cursor[i] = e + 1;                    // slot e holds the self record
        float d = dis[i];
        int2 r; r.x = i; r.y = f2i(2.0f * d * d);
        recs[e] = r;
    }
}

// XCD-partitioned fill; writes (src, dis[src]*dis[dst]) records
__global__ __launch_bounds__(256) void fill_xcd(const int* __restrict__ ei, int E, int nper,
                                                const float* __restrict__ dis,
                                                int* __restrict__ cursor, int2* __restrict__ recs) {
    int xcd = blockIdx.x & 7;
    int nchunk = gridDim.x >> 3;
    int chunk = blockIdx.x >> 3;
    int csz = (E + nchunk - 1) / nchunk;
    int beg = chunk * csz;
    int end = min(E, beg + csz);
    for (int e = beg + (int)threadIdx.x; e < end; e += 256) {
        int c = ei[E + e];
        if (c / nper == xcd) {
            int r = ei[e];
            int slot = atomicAdd(&cursor[c], 1);
            int2 rec; rec.x = r; rec.y = f2i(dis[r] * dis[c]);
            recs[slot] = rec;
        }
    }
}

// ---------------- weight prep: transpose + bf16 (also zeroes cnt + stats) ----------------

__global__ __launch_bounds__(256) void prep_weights(const float* __restrict__ W0, const float* __restrict__ pW,
                                                    const float* __restrict__ W1, const float* __restrict__ hW,
                                                    ushortT* __restrict__ Wt0, ushortT* __restrict__ WtP,
                                                    ushortT* __restrict__ Wt1, ushortT* __restrict__ WtH,
                                                    int* __restrict__ cnt, float* __restrict__ stats, int N) {
    int i = blockIdx.x * 256 + threadIdx.x;
    if (i < 32768) { int n = i >> 8, k = i & 255; Wt0[i] = f2bf(W0[k * 128 + n]); WtP[i] = f2bf(pW[k * 128 + n]); }
    if (i < 16384) { int n = i >> 7, k = i & 127; Wt1[i] = f2bf(W1[k * 128 + n]); }
    if (i < 6144)  { int n = i >> 7, k = i & 127; WtH[i] = (n < OUT_DIM) ? f2bf(hW[k * OUT_DIM + n]) : (ushortT)0; }
    if (i < N) cnt[i] = 0;
    if (i < 512) stats[i] = 0.f;
}

// ---------------- GEMM0: dual (h = x@W0, proj = x@pW + pb), K=256 in 2 dbuf chunks, LDS epilogue ----------------
// 512 threads (8 waves), BM=64. waves 0-3: W0 -> Oh; waves 4-7: pW -> Op. wave cols = (w&3)*32 + [0,32).
// B entirely in regs (64 VGPR/thread). LDS: S2[2][64*136] = A chunk dbuf; reused as C[2][64][136] in epilogue.

static __device__ __forceinline__ void g0_loads(const float* __restrict__ X, int brow, int kc,
                                                int tid, int N, float4 pf[4]) {
#pragma unroll
    for (int i = 0; i < 4; ++i) {
        int idx = i * 512 + tid;
        int row = idx >> 5, c4 = idx & 31;
        int gr = brow + row;
        pf[i] = make_float4(0.f, 0.f, 0.f, 0.f);
        if (gr < N) pf[i] = *(const float4*)&X[(size_t)gr * IN_DIM + kc * 128 + c4 * 4];
    }
}
static __device__ __forceinline__ void g0_write(ushortT* __restrict__ Sbuf, int tid, const float4 pf[4]) {
#pragma unroll
    for (int i = 0; i < 4; ++i) {
        int idx = i * 512 + tid;
        int row = idx >> 5, c4 = idx & 31;
        uint2 p;
        p.x = pk2(pf[i].x, pf[i].y);
        p.y = pk2(pf[i].z, pf[i].w);
        *(uint2*)&Sbuf[row * 136 + c4 * 4] = p;
    }
}

__global__ __launch_bounds__(512) void mgemm0d(const float* __restrict__ X,
                                               const ushortT* __restrict__ Wt0,
                                               const ushortT* __restrict__ WtP,
                                               const float* __restrict__ pb,
                                               ushortT* __restrict__ Oh,
                                               ushortT* __restrict__ Op,
                                               int N) {
    __shared__ __align__(16) ushortT S2[2][64 * 136];
    int tid = threadIdx.x;
    int brow = blockIdx.x * 64;
    int w = tid >> 6, lane = tid & 63;
    int lm = lane & 15, lk = lane >> 4;
    int mat = w >> 2;
    int colbase = (w & 3) * 32;
    const ushortT* Wt = mat ? WtP : Wt0;

    // B in regs for the whole tile (hidden under chunk0 staging latency)
    bf16x8 breg[2][8];
#pragma unroll
    for (int nt = 0; nt < 2; ++nt)
#pragma unroll
        for (int kk = 0; kk < 8; ++kk)
            breg[nt][kk] = *(const bf16x8*)&Wt[(size_t)(colbase + nt * 16 + lm) * IN_DIM + kk * 32 + lk * 8];
    float bb[2];
    bb[0] = mat ? pb[colbase + lm] : 0.f;
    bb[1] = mat ? pb[colbase + 16 + lm] : 0.f;

    float4 pf[4];
    g0_loads(X, brow, 0, tid, N, pf);
    g0_write(S2[0], tid, pf);
    __syncthreads();                                   // buf0 staged
    g0_loads(X, brow, 1, tid, N, pf);                  // issue chunk1 early

    f32x4 acc[4][2];
#pragma unroll
    for (int mt = 0; mt < 4; ++mt)
#pragma unroll
        for (int nt = 0; nt < 2; ++nt) acc[mt][nt] = (f32x4)0.f;

    // MFMA chunk 0
#pragma unroll
    for (int kk = 0; kk < 4; ++kk) {
        bf16x8 af[4];
#pragma unroll
        for (int mt = 0; mt < 4; ++mt)
            af[mt] = *(const bf16x8*)&S2[0][(mt * 16 + lm) * 136 + kk * 32 + lk * 8];
#pragma unroll
        for (int nt = 0; nt < 2; ++nt)
#pragma unroll
            for (int mt = 0; mt < 4; ++mt)
                acc[mt][nt] = __builtin_amdgcn_mfma_f32_16x16x32_bf16(af[mt], breg[nt][kk], acc[mt][nt], 0, 0, 0);
    }
    g0_write(S2[1], tid, pf);
    __syncthreads();                                   // buf1 staged
    // MFMA chunk 1
#pragma unroll
    for (int kk = 0; kk < 4; ++kk) {
        bf16x8 af[4];
#pragma unroll
        for (int mt = 0; mt < 4; ++mt)
            af[mt] = *(const bf16x8*)&S2[1][(mt * 16 + lm) * 136 + kk * 32 + lk * 8];
#pragma unroll
        for (int nt = 0; nt < 2; ++nt)
#pragma unroll
            for (int mt = 0; mt < 4; ++mt)
                acc[mt][nt] = __builtin_amdgcn_mfma_f32_16x16x32_bf16(af[mt], breg[nt][4 + kk], acc[mt][nt], 0, 0, 0);
    }
    __syncthreads();                                   // all LDS reads done; reuse as C
    // C staging: mat m -> S2[m], row stride 136
#pragma unroll
    for (int mt = 0; mt < 4; ++mt)
#pragma unroll
        for (int nt = 0; nt < 2; ++nt) {
            int col = colbase + nt * 16 + lm;
#pragma unroll
            for (int j = 0; j < 4; ++j) {
                int row = mt * 16 + lk * 4 + j;
                S2[mat][row * 136 + col] = f2bf(acc[mt][nt][j] + bb[nt]);
            }
        }
    __syncthreads();
    // coalesced stores: 2048 uint4 (2 mats x 64 rows x 16 uint4), 4/thread
#pragma unroll
    for (int i = 0; i < 4; ++i) {
        int idx = i * 512 + tid;
        int m2 = idx >> 10;
        int rem = idx & 1023;
        int row = rem >> 4, colq = rem & 15;
        int gr = brow + row;
        if (gr < N) {
            uint4 v = *(const uint4*)&S2[m2][row * 136 + colq * 8];
            ushortT* O = m2 ? Op : Oh;
            *(uint4*)&O[(size_t)gr * 128 + colq * 8] = v;
        }
    }
}

// ---------------- GEMM1 fused: x1 = relu(bn0(agg)) + proj (written out), h = x1 @ W1, LDS epilogue ----------------

__global__ __launch_bounds__(512) void mgemm1_fused(const uint4* __restrict__ aggb,
                                                    const uint4* __restrict__ projb,
                                                    const float* __restrict__ stats,
                                                    const float* __restrict__ g,
                                                    const float* __restrict__ be,
                                                    const ushortT* __restrict__ Wt1,
                                                    ushortT* __restrict__ O,
                                                    uint4* __restrict__ x1b,
                                                    int N) {
    __shared__ __align__(16) ushortT S[17408];
    __shared__ float sc[128], sh[128];
    int tid = threadIdx.x;
    int brow = blockIdx.x * 128;

    if (tid < 128) {
        float mean = stats[tid] / (float)N;
        float var = stats[128 + tid] / (float)N - mean * mean;
        float inv = rsqrtf(var + EPS);
        float s = g[tid] * inv;
        sc[tid] = s;
        sh[tid] = be[tid] - mean * s;
    }
    __syncthreads();

#pragma unroll
    for (int i = 0; i < 4; ++i) {
        int idx = i * 512 + tid;
        int row = idx >> 4, q = idx & 15;
        int gr = brow + row;
        uint4 a = make_uint4(0u, 0u, 0u, 0u), p = a;
        if (gr < N) {
            size_t gidx = (size_t)gr * 16 + q;
            a = aggb[gidx];
            p = projb[gidx];
        }
        int ch = q * 8;
        float v0 = fmaxf(fmaf(bflo(a.x), sc[ch + 0], sh[ch + 0]), 0.f) + bflo(p.x);
        float v1 = fmaxf(fmaf(bfhi(a.x), sc[ch + 1], sh[ch + 1]), 0.f) + bfhi(p.x);
        float v2 = fmaxf(fmaf(bflo(a.y), sc[ch + 2], sh[ch + 2]), 0.f) + bflo(p.y);
        float v3 = fmaxf(fmaf(bfhi(a.y), sc[ch + 3], sh[ch + 3]), 0.f) + bfhi(p.y);
        float v4 = fmaxf(fmaf(bflo(a.z), sc[ch + 4], sh[ch + 4]), 0.f) + bflo(p.z);
        float v5 = fmaxf(fmaf(bfhi(a.z), sc[ch + 5], sh[ch + 5]), 0.f) + bfhi(p.z);
        float v6 = fmaxf(fmaf(bflo(a.w), sc[ch + 6], sh[ch + 6]), 0.f) + bflo(p.w);
        float v7 = fmaxf(fmaf(bfhi(a.w), sc[ch + 7], sh[ch + 7]), 0.f) + bfhi(p.w);
        uint4 pv;
        pv.x = pk2(v0, v1);
        pv.y = pk2(v2, v3);
        pv.z = pk2(v4, v5);
        pv.w = pk2(v6, v7);
        *(uint4*)&S[row * 136 + q * 8] = pv;
        if (gr < N) x1b[(size_t)gr * 16 + q] = pv;
    }
    __syncthreads();

    int w = tid >> 6, lane = tid & 63;
    int lm = lane & 15, lk = lane >> 4;
    int rh = (w >> 2) * 64;
    int colbase = (w & 3) * 32;

    bf16x8 breg[2][4];
#pragma unroll
    for (int nt = 0; nt < 2; ++nt)
#pragma unroll
        for (int ks = 0; ks < 4; ++ks)
            breg[nt][ks] = *(const bf16x8*)&Wt1[(size_t)(colbase + nt * 16 + lm) * H + ks * 32 + lk * 8];

    f32x4 acc[4][2];
#pragma unroll
    for (int mt = 0; mt < 4; ++mt)
#pragma unroll
        for (int nt = 0; nt < 2; ++nt) acc[mt][nt] = (f32x4)0.f;

#pragma unroll
    for (int ks = 0; ks < 4; ++ks) {
        bf16x8 af[4];
#pragma unroll
        for (int mt = 0; mt < 4; ++mt)
            af[mt] = *(const bf16x8*)&S[(rh + mt * 16 + lm) * 136 + ks * 32 + lk * 8];
#pragma unroll
        for (int nt = 0; nt < 2; ++nt)
#pragma unroll
            for (int mt = 0; mt < 4; ++mt)
                acc[mt][nt] = __builtin_amdgcn_mfma_f32_16x16x32_bf16(af[mt], breg[nt][ks], acc[mt][nt], 0, 0, 0);
    }

    __syncthreads();
#pragma unroll
    for (int mt = 0; mt < 4; ++mt)
#pragma unroll
        for (int nt = 0; nt < 2; ++nt) {
            int col = colbase + nt * 16 + lm;
#pragma unroll
            for (int j = 0; j < 4; ++j) {
                int row = rh + mt * 16 + lk * 4 + j;
                S[row * 136 + col] = f2bf(acc[mt][nt][j]);
            }
        }
    __syncthreads();
#pragma unroll
    for (int i = 0; i < 4; ++i) {
        int idx = i * 512 + tid;
        int row = idx >> 4, colq = idx & 15;
        int gr = brow + row;
        if (gr < N) {
            uint4 v = *(const uint4*)&S[row * 136 + colq * 8];
            *(uint4*)&O[(size_t)gr * 128 + colq * 8] = v;
        }
    }
}

// ---------------- aggregation: wave per node, half-wave edge split, premult records ----------------

__global__ __launch_bounds__(256) void aggregate_rec(const ushortT* __restrict__ h,
                                                     const int* __restrict__ rowptr,
                                                     const int2* __restrict__ recs,
                                                     ushortT* __restrict__ aggb, int N) {
    int n = blockIdx.x * 4 + (threadIdx.x >> 6);
    if (n >= N) return;
    int lane = threadIdx.x & 63;
    int half = lane >> 5, cl = lane & 31;
    int beg = rowptr[n], end = rowptr[n + 1];
    const uint2* h2 = (const uint2*)h;           // 8B units; row stride 32
    float a0 = 0.f, a1 = 0.f, a2 = 0.f, a3 = 0.f;
    float b0 = 0.f, b1 = 0.f, b2 = 0.f, b3 = 0.f;
    int idx = beg + half;
    for (; idx + 2 < end; idx += 4) {
        int2 r0 = recs[idx];
        int2 r1 = recs[idx + 2];
        uint2 v0 = h2[(size_t)r0.x * 32 + cl];
        uint2 v1 = h2[(size_t)r1.x * 32 + cl];
        float n0 = i2f(r0.y), n1 = i2f(r1.y);
        a0 = fmaf(n0, bflo(v0.x), a0); a1 = fmaf(n0, bfhi(v0.x), a1);
        a2 = fmaf(n0, bflo(v0.y), a2); a3 = fmaf(n0, bfhi(v0.y), a3);
        b0 = fmaf(n1, bflo(v1.x), b0); b1 = fmaf(n1, bfhi(v1.x), b1);
        b2 = fmaf(n1, bflo(v1.y), b2); b3 = fmaf(n1, bfhi(v1.y), b3);
    }
    if (idx < end) {
        int2 r0 = recs[idx];
        uint2 v0 = h2[(size_t)r0.x * 32 + cl];
        float n0 = i2f(r0.y);
        a0 = fmaf(n0, bflo(v0.x), a0); a1 = fmaf(n0, bfhi(v0.x), a1);
        a2 = fmaf(n0, bflo(v0.y), a2); a3 = fmaf(n0, bfhi(v0.y), a3);
    }
    a0 += b0; a1 += b1; a2 += b2; a3 += b3;
    a0 += __shfl_xor(a0, 32);
    a1 += __shfl_xor(a1, 32);
    a2 += __shfl_xor(a2, 32);
    a3 += __shfl_xor(a3, 32);
    if (half == 0) {
        uint2 o;
        o.x = pk2(a0, a1);
        o.y = pk2(a2, a3);
        ((uint2*)aggb)[(size_t)n * 32 + cl] = o;
    }
}

// ---------------- BN stats from bf16 (raw sums) ----------------

__global__ __launch_bounds__(256) void stats_bf(const unsigned* __restrict__ v, int totalU,
                                                float* __restrict__ sums) {
    int tid = blockIdx.x * 256 + threadIdx.x;
    int stride = gridDim.x * 256;
    float sx = 0.f, sy = 0.f, qx = 0.f, qy = 0.f;
    for (int i = tid; i < totalU; i += stride) {
        unsigned u = v[i];
        float a = bflo(u), b = bfhi(u);
        sx += a; sy += b;
        qx = fmaf(a, a, qx); qy = fmaf(b, b, qy);
    }
    __shared__ float l0[256], l1[256], l2[256], l3[256];
    int t = threadIdx.x;
    l0[t] = sx; l1[t] = sy; l2[t] = qx; l3[t] = qy;
    __syncthreads();
    if (t < 64) {
        sx = (l0[t] + l0[t + 64]) + (l0[t + 128] + l0[t + 192]);
        sy = (l1[t] + l1[t + 64]) + (l1[t + 128] + l1[t + 192]);
        qx = (l2[t] + l2[t + 64]) + (l2[t + 128] + l2[t + 192]);
        qy = (l3[t] + l3[t + 64]) + (l3[t + 128] + l3[t + 192]);
        atomicAdd(&sums[2 * t], sx);
        atomicAdd(&sums[2 * t + 1], sy);
        atomicAdd(&sums[128 + 2 * t], qx);
        atomicAdd(&sums[128 + 2 * t + 1], qy);
    }
}

// ---------------- head: out = (relu(bn1(agg)) + x1) @ hW + hb, x2 inline ----------------

__global__ __launch_bounds__(256) void head_fused(const uint4* __restrict__ aggb,
                                                  const uint4* __restrict__ x1b,
                                                  const float* __restrict__ stats,
                                                  const float* __restrict__ g,
                                                  const float* __restrict__ be,
                                                  const ushortT* __restrict__ WtH,
                                                  const float* __restrict__ hb,
                                                  float* __restrict__ out, int N) {
    __shared__ __align__(16) ushortT As[64][136];
    __shared__ __align__(16) ushortT Bs[48][136];
    __shared__ float sc[128], sh[128];

    int tid = threadIdx.x;
    int brow = blockIdx.x * 64;
    int w = tid >> 6, lane = tid & 63;
    int lm = lane & 15, lk = lane >> 4;

    if (tid < 128) {
        float mean = stats[tid] / (float)N;
        float var = stats[128 + tid] / (float)N - mean * mean;
        float inv = rsqrtf(var + EPS);
        float s = g[tid] * inv;
        sc[tid] = s;
        sh[tid] = be[tid] - mean * s;
    }
    if (tid < 192) {
        int row = tid >> 2, q = tid & 3;
        const uint4* src = (const uint4*)&WtH[(size_t)row * H + q * 32];
        uint4 a = src[0], b = src[1], c = src[2], d = src[3];
        uint4* dst = (uint4*)&Bs[row][q * 32];
        dst[0] = a; dst[1] = b; dst[2] = c; dst[3] = d;
    }
    __syncthreads();
#pragma unroll
    for (int k = 0; k < 4; ++k) {
        int idx = k * 256 + tid;
        int row = idx >> 4, colq = idx & 15;
        int gr = brow + row;
        uint4 a = make_uint4(0u, 0u, 0u, 0u), x = a;
        if (gr < N) {
            size_t gidx = (size_t)brow * 16 + idx;
            a = aggb[gidx];
            x = x1b[gidx];
        }
        int ch = colq * 8;
        float v0 = fmaxf(fmaf(bflo(a.x), sc[ch + 0], sh[ch + 0]), 0.f) + bflo(x.x);
        float v1 = fmaxf(fmaf(bfhi(a.x), sc[ch + 1], sh[ch + 1]), 0.f) + bfhi(x.x);
        float v2 = fmaxf(fmaf(bflo(a.y), sc[ch + 2], sh[ch + 2]), 0.f) + bflo(x.y);
        float v3 = fmaxf(fmaf(bfhi(a.y), sc[ch + 3], sh[ch + 3]), 0.f) + bfhi(x.y);
        float v4 = fmaxf(fmaf(bflo(a.z), sc[ch + 4], sh[ch + 4]), 0.f) + bflo(x.z);
        float v5 = fmaxf(fmaf(bfhi(a.z), sc[ch + 5], sh[ch + 5]), 0.f) + bfhi(x.z);
        float v6 = fmaxf(fmaf(bflo(a.w), sc[ch + 6], sh[ch + 6]), 0.f) + bflo(x.w);
        float v7 = fmaxf(fmaf(bfhi(a.w), sc[ch + 7], sh[ch + 7]), 0.f) + bfhi(x.w);
        uint4 pv;
        pv.x = pk2(v0, v1);
        pv.y = pk2(v2, v3);
        pv.z = pk2(v4, v5);
        pv.w = pk2(v6, v7);
        *(uint4*)&As[row][colq * 8] = pv;
    }
    __syncthreads();

    f32x4 acc[3];
#pragma unroll
    for (int nt = 0; nt < 3; ++nt) acc[nt] = (f32x4)0.f;
#pragma unroll
    for (int ks = 0; ks < 4; ++ks) {
        bf16x8 a = *(const bf16x8*)&As[w * 16 + lm][ks * 32 + lk * 8];
#pragma unroll
        for (int nt = 0; nt < 3; ++nt) {
            bf16x8 b = *(const bf16x8*)&Bs[nt * 16 + lm][ks * 32 + lk * 8];
            acc[nt] = __builtin_amdgcn_mfma_f32_16x16x32_bf16(a, b, acc[nt], 0, 0, 0);
        }
    }
#pragma unroll
    for (int nt = 0; nt < 3; ++nt) {
        int col = nt * 16 + lm;
        if (col < OUT_DIM) {
            float bbv = hb[col];
#pragma unroll
            for (int j = 0; j < 4; ++j) {
                int r = brow + w * 16 + lk * 4 + j;
                if (r < N) out[(size_t)r * OUT_DIM + col] = acc[nt][j] + bbv;
            }
        }
    }
}

// ---------------- launch ----------------

extern "C" void kernel_launch(void* const* d_in, const int* in_sizes, int n_in,
                              void* d_out, int out_size, void* d_ws, size_t ws_size,
                              hipStream_t stream) {
    const float* x   = (const float*)d_in[0];
    const int*   ei  = (const int*)d_in[1];
    const float* W0  = (const float*)d_in[2];
    // d_in[3] = b0: cancels in BatchNorm
    const float* g0  = (const float*)d_in[4];
    const float* be0 = (const float*)d_in[5];
    const float* pW  = (const float*)d_in[6];
    const float* pb  = (const float*)d_in[7];
    const float* W1  = (const float*)d_in[8];
    // d_in[9] = b1: cancels in BatchNorm
    const float* g1  = (const float*)d_in[10];
    const float* be1 = (const float*)d_in[11];
    const float* hW  = (const float*)d_in[12];
    const float* hb  = (const float*)d_in[13];
    float* out = (float*)d_out;

    int N = in_sizes[0] / IN_DIM;
    int E = in_sizes[1] / 2;
    size_t NH = (size_t)N * H;

    // workspace layout (all bf16 intermediates)
    ushortT* hb16   = (ushortT*)d_ws;            // [N,128] conv input h
    ushortT* aggb   = hb16 + NH;                 // [N,128] aggregated
    ushortT* projb  = aggb + NH;                 // [N,128] proj (block0)
    ushortT* x1b    = projb + NH;                // [N,128] x1
    float*   dis    = (float*)(x1b + NH);        // [N]
    int*     cnt    = (int*)(dis + N);           // [N]
    int*     rowptr = cnt + N;                   // [N+1]
    int*     cursor = rowptr + (N + 1);          // [N]
    int2*    recs   = (int2*)(cursor + N);       // [E+N] (8B-aligned)
    float*   stats  = (float*)(recs + (E + N));  // [512]: block0 then block1
    ushortT* Wt0    = (ushortT*)(stats + 512);   // [128*256]
    ushortT* WtP    = Wt0 + 128 * 256;           // [128*256]
    ushortT* Wt1    = WtP + 128 * 256;           // [128*128]
    ushortT* WtH    = Wt1 + 128 * 128;           // [48*128]
    int*     bsum   = (int*)(WtH + 48 * 128);    // [256]
    int*     boff   = bsum + 256;                // [256]
    float*   stats0 = stats;
    float*   stats1 = stats + 256;

    int nb = (N + 255) / 256;
    int g64 = (N + 63) / 64;
    int g128 = (N + 127) / 128;
    int gAgg = (N + 3) / 4;

    // prep (weights + zero cnt/stats), CSR build
    prep_weights<<<196, 256, 0, stream>>>(W0, pW, W1, hW, Wt0, WtP, Wt1, WtH, cnt, stats, N);
    count_xcd<<<2048, 256, 0, stream>>>(ei, E, (N + 7) / 8, cnt);
    scan_block_sum<<<nb, 256, 0, stream>>>(cnt, bsum, dis, N);
    scan_tops<<<1, 256, 0, stream>>>(bsum, boff, &rowptr[N], nb);
    scan_final<<<nb, 256, 0, stream>>>(cnt, boff, dis, rowptr, cursor, recs, N);
    fill_xcd<<<2048, 256, 0, stream>>>(ei, E, (N + 7) / 8, dis, cursor, recs);

    // block 0
    mgemm0d<<<g64, 512, 0, stream>>>(x, Wt0, WtP, pb, hb16, projb, N);
    aggregate_rec<<<gAgg, 256, 0, stream>>>(hb16, rowptr, recs, aggb, N);
    stats_bf<<<256, 256, 0, stream>>>((const unsigned*)aggb, (int)(NH / 2), stats0);

    // block 1 (x1 = relu(bn0(agg)) + proj fused into GEMM1's staging; x1 also written for head)
    mgemm1_fused<<<g128, 512, 0, stream>>>((const uint4*)aggb, (const uint4*)projb, stats0, g0, be0,
                                           Wt1, hb16, (uint4*)x1b, N);
    aggregate_rec<<<gAgg, 256, 0, stream>>>(hb16, rowptr, recs, aggb, N);
    stats_bf<<<256, 256, 0, stream>>>((const unsigned*)aggb, (int)(NH / 2), stats1);

    // head (x2 computed inline)
    head_fused<<<g64, 256, 0, stream>>>((const uint4*)aggb, (const uint4*)x1b, stats1, g1, be1,
                                        WtH, hb, out, N);
}